// Round 7
// baseline (896.334 us; speedup 1.0000x reference)
//
#include <hip/hip_runtime.h>
#include <stdint.h>

typedef unsigned short u16;
typedef unsigned int u32;
typedef __bf16 bf16x8 __attribute__((ext_vector_type(8)));
typedef float f32x4 __attribute__((ext_vector_type(4)));
typedef float f32x16 __attribute__((ext_vector_type(16)));
typedef u16 u16x4 __attribute__((ext_vector_type(4)));
typedef u16 u16x8 __attribute__((ext_vector_type(8)));

#define MFMA16(a, b, c) __builtin_amdgcn_mfma_f32_16x16x32_bf16(a, b, c, 0, 0, 0)
#define MFMA32(a, b, c) __builtin_amdgcn_mfma_f32_32x32x16_bf16(a, b, c, 0, 0, 0)

__device__ __forceinline__ u16 f2bf(float f) {
  u32 u = __builtin_bit_cast(u32, f);
  u += 0x7FFFu + ((u >> 16) & 1u);
  return (u16)(u >> 16);
}

__device__ __forceinline__ bf16x8 ld16(const u16* p) {
  return __builtin_bit_cast(bf16x8, *(const uint4*)p);
}

__device__ __forceinline__ void gl_lds(const u16* src, u16* lds) {
  __builtin_amdgcn_global_load_lds(
      (const __attribute__((address_space(1))) u32*)src,
      (__attribute__((address_space(3))) u32*)lds, 16, 0, 0);
}

// ---------------- weight conversion (once per launch) ----------------
__global__ __launch_bounds__(256) void convert_weights(
    const float* __restrict__ Wq, const float* __restrict__ Wk,
    const float* __restrict__ Wv, const float* __restrict__ fcw,
    u16* __restrict__ wq_b, u16* __restrict__ wk_b, u16* __restrict__ wv_b,
    u16* __restrict__ fcw_b) {
  int bx = blockIdx.x, tid = threadIdx.x;
  if (bx < 4096) {
    int i = (bx * 256 + tid) * 4;
    float4 f = *(const float4*)&fcw[i];
    u16x4 o = {f2bf(f.x), f2bf(f.y), f2bf(f.z), f2bf(f.w)};
    *(u16x4*)&fcw_b[i] = o;
  } else {
    int i = ((bx - 4096) * 256 + tid) * 4;
    const float sc = 0.022097086912079612f;  // 1/sqrt(2048) folded into Wq
    float4 q = *(const float4*)&Wq[i];
    u16x4 oq = {f2bf(q.x * sc), f2bf(q.y * sc), f2bf(q.z * sc), f2bf(q.w * sc)};
    *(u16x4*)&wq_b[i] = oq;
    float4 k = *(const float4*)&Wk[i];
    u16x4 ok = {f2bf(k.x), f2bf(k.y), f2bf(k.z), f2bf(k.w)};
    *(u16x4*)&wk_b[i] = ok;
    float4 v = *(const float4*)&Wv[i];
    u16x4 ov = {f2bf(v.x), f2bf(v.y), f2bf(v.z), f2bf(v.w)};
    *(u16x4*)&wv_b[i] = ov;
  }
}

// ---------------- QKV projection, 2 heads per block ----------------
__global__ __launch_bounds__(768) void qkv_kernel(
    const float* __restrict__ srcF, const u16* __restrict__ srcB, int srcf32,
    const u16* __restrict__ wq, const u16* __restrict__ wk,
    const u16* __restrict__ wvw, u16* __restrict__ Q, u16* __restrict__ K,
    u16* __restrict__ Vt, int bsh) {
  __shared__ u16 X[64 * 264];
  int jt = blockIdx.x, i0 = blockIdx.y, n = blockIdx.z;
  int tid = threadIdx.x;
#pragma unroll
  for (int it = 0; it < 3; ++it) {
    int c = tid + it * 768;
    if (c < 2048) {
      int row = c >> 5, seg = c & 31;
      int pos = (8 * (jt * 64 + row) + i0 - bsh) & 4095;
      size_t base = ((size_t)n * 4096 + pos) * 256 + seg * 8;
      if (srcf32) {
        float4 f0 = *(const float4*)&srcF[base];
        float4 f1 = *(const float4*)&srcF[base + 4];
        u16x8 v = {f2bf(f0.x), f2bf(f0.y), f2bf(f0.z), f2bf(f0.w),
                   f2bf(f1.x), f2bf(f1.y), f2bf(f1.z), f2bf(f1.w)};
        *(u16x8*)&X[row * 264 + seg * 8] = v;
      } else {
        *(u16x8*)&X[row * 264 + seg * 8] = *(const u16x8*)&srcB[base];
      }
    }
  }
  __syncthreads();
  int wvid = tid >> 6, ln = tid & 63;
  int mat = wvid >> 2, hc = wvid & 3;
  int hh = hc >> 1, cb = (hc & 1) * 64;
  int h = i0 * 2 + hh, xc = hh * 128;
  const u16* W = (mat == 0) ? wq : (mat == 1) ? wk : wvw;
  int lr = ln & 15, lg = ln >> 4;
  f32x4 acc[4][4] = {};
#pragma unroll
  for (int kt = 0; kt < 4; ++kt) {
    bf16x8 a[4], b[4];
#pragma unroll
    for (int mt = 0; mt < 4; ++mt)
      a[mt] = ld16(&X[(mt * 16 + lr) * 264 + xc + kt * 32 + lg * 8]);
#pragma unroll
    for (int nc = 0; nc < 4; ++nc)
      b[nc] = ld16(&W[(cb + nc * 16 + lr) * 128 + kt * 32 + lg * 8]);
#pragma unroll
    for (int mt = 0; mt < 4; ++mt)
#pragma unroll
      for (int nc = 0; nc < 4; ++nc)
        acc[mt][nc] = MFMA16(a[mt], b[nc], acc[mt][nc]);
  }
  size_t nh = (size_t)(n * 16 + h);
  if (mat < 2) {
    u16* dst = (mat == 0 ? Q : K) + nh * 512 * 128;
#pragma unroll
    for (int mt = 0; mt < 4; ++mt)
#pragma unroll
      for (int nc = 0; nc < 4; ++nc) {
        int col = cb + nc * 16 + lr;
        int jb = jt * 64 + mt * 16 + lg * 4;
#pragma unroll
        for (int r = 0; r < 4; ++r)
          dst[(size_t)(jb + r) * 128 + col] = f2bf(acc[mt][nc][r]);
      }
  } else {
    u16* dst = Vt + nh * 128 * 512;
#pragma unroll
    for (int mt = 0; mt < 4; ++mt)
#pragma unroll
      for (int nc = 0; nc < 4; ++nc) {
        int col = cb + nc * 16 + lr;
        int jb = jt * 64 + mt * 16 + lg * 4;
        u16x4 pk = {f2bf(acc[mt][nc][0]), f2bf(acc[mt][nc][1]),
                    f2bf(acc[mt][nc][2]), f2bf(acc[mt][nc][3])};
        *(u16x4*)&dst[(size_t)col * 512 + jb] = pk;
      }
  }
}

// ---------------- flash attention: LDS-staged K/V, in-register softmax ----
__global__ __launch_bounds__(256, 2) void attn_kernel(
    const u16* __restrict__ Q, const u16* __restrict__ K,
    const u16* __restrict__ Vt, u16* __restrict__ O) {
  __shared__ u16 KL[2][64 * 128];
  __shared__ u16 VL[2][128 * 64];
  int flat = blockIdx.x;
  int xcd = flat & 7, idx = flat >> 3;
  int gl = idx & 15, qt = idx >> 4;
  int g = xcd | (gl << 3);
  int h = g & 15, n = g >> 4;
  int tid = threadIdx.x, wv = tid >> 6, ln = tid & 63;
  int l31 = ln & 31, hh = ln >> 5;
  size_t nh = (size_t)(n * 16 + h);
  int q0 = qt * 128 + wv * 32;
  const u16* Qb = Q + ((size_t)nh * 512 + q0) * 128;
  const u16* Kb = K + (size_t)nh * 512 * 128;
  const u16* Vb = Vt + (size_t)nh * 128 * 512;

  bf16x8 qf[8];
#pragma unroll
  for (int kt = 0; kt < 8; ++kt)
    qf[kt] = ld16(&Qb[l31 * 128 + kt * 16 + hh * 8]);

  int l16 = ln & 15, l8 = ln & 7;
  int rK[4], cK[4], rV[4], cV[4];
#pragma unroll
  for (int i = 0; i < 4; ++i) {
    int s = wv * 4 + i;
    rK[i] = 4 * s + (ln >> 4);
    cK[i] = (l16 ^ (rK[i] & 15)) * 8;
    rV[i] = 8 * s + (ln >> 3);
    cV[i] = (l8 ^ (rV[i] & 7)) * 8;
  }

#pragma unroll
  for (int i = 0; i < 4; ++i) {
    int s = wv * 4 + i;
    gl_lds(&Kb[(size_t)rK[i] * 128 + cK[i]], &KL[0][s * 512]);
    gl_lds(&Vb[(size_t)rV[i] * 512 + 0 * 64 + cV[i]], &VL[0][s * 512]);
  }
  __syncthreads();

  f32x16 o[4] = {};
  float m = -1e30f, l = 0.f;

  for (int kv = 0; kv < 8; ++kv) {
    int cur = kv & 1;
    if (kv < 7) {
      int nxt = cur ^ 1;
      const u16* kp = Kb + (size_t)(kv + 1) * 64 * 128;
#pragma unroll
      for (int i = 0; i < 4; ++i) {
        int s = wv * 4 + i;
        gl_lds(&kp[(size_t)rK[i] * 128 + cK[i]], &KL[nxt][s * 512]);
        gl_lds(&Vb[(size_t)rV[i] * 512 + (kv + 1) * 64 + cV[i]], &VL[nxt][s * 512]);
      }
    }
    f32x16 s[2] = {};
    __builtin_amdgcn_s_setprio(1);
#pragma unroll
    for (int kb = 0; kb < 2; ++kb)
#pragma unroll
      for (int kt = 0; kt < 8; ++kt) {
        int row = kb * 32 + l31;
        int slot = (2 * kt + hh) ^ (row & 15);
        bf16x8 a = ld16(&KL[cur][row * 128 + slot * 8]);
        s[kb] = MFMA32(a, qf[kt], s[kb]);
      }
    __builtin_amdgcn_s_setprio(0);
    float mx[8];
#pragma unroll
    for (int i = 0; i < 8; ++i)
      mx[i] = fmaxf(fmaxf(s[0][2 * i], s[0][2 * i + 1]),
                    fmaxf(s[1][2 * i], s[1][2 * i + 1]));
    float pm = fmaxf(fmaxf(fmaxf(mx[0], mx[1]), fmaxf(mx[2], mx[3])),
                     fmaxf(fmaxf(mx[4], mx[5]), fmaxf(mx[6], mx[7])));
    pm = fmaxf(pm, __shfl_xor(pm, 32));
    if (!__all(pm <= m + 8.f)) {
      float nm = fmaxf(m, pm);
      float al = __expf(m - nm);
      l *= al;
      m = nm;
#pragma unroll
      for (int r = 0; r < 16; ++r) {
        int qr = (r & 3) + 8 * (r >> 2) + 4 * hh;
        float av = __shfl(al, (ln & 32) | qr, 64);
        o[0][r] *= av; o[1][r] *= av; o[2][r] *= av; o[3][r] *= av;
      }
    }
#pragma unroll
    for (int kb = 0; kb < 2; ++kb)
#pragma unroll
      for (int r = 0; r < 16; ++r) s[kb][r] = __expf(s[kb][r] - m);
    float sm[8];
#pragma unroll
    for (int i = 0; i < 8; ++i)
      sm[i] = (s[0][2 * i] + s[0][2 * i + 1]) + (s[1][2 * i] + s[1][2 * i + 1]);
    float rs = ((sm[0] + sm[1]) + (sm[2] + sm[3])) +
               ((sm[4] + sm[5]) + (sm[6] + sm[7]));
    rs += __shfl_xor(rs, 32);
    l += rs;
    bf16x8 pa[4];
#pragma unroll
    for (int ks = 0; ks < 4; ++ks) {
      const int kb = ks >> 1, r0 = 8 * (ks & 1);
      u32 wA, wB, wC, wD;
      asm("v_cvt_pk_bf16_f32 %0, %1, %2" : "=v"(wA) : "v"(s[kb][r0 + 0]), "v"(s[kb][r0 + 1]));
      asm("v_cvt_pk_bf16_f32 %0, %1, %2" : "=v"(wB) : "v"(s[kb][r0 + 2]), "v"(s[kb][r0 + 3]));
      asm("v_cvt_pk_bf16_f32 %0, %1, %2" : "=v"(wC) : "v"(s[kb][r0 + 4]), "v"(s[kb][r0 + 5]));
      asm("v_cvt_pk_bf16_f32 %0, %1, %2" : "=v"(wD) : "v"(s[kb][r0 + 6]), "v"(s[kb][r0 + 7]));
      asm("v_permlane32_swap_b32 %0, %1" : "+v"(wA), "+v"(wC));
      asm("v_permlane32_swap_b32 %0, %1" : "+v"(wB), "+v"(wD));
      uint4 ww = {wA, wB, wC, wD};
      pa[ks] = __builtin_bit_cast(bf16x8, ww);
    }
    __builtin_amdgcn_s_setprio(1);
#pragma unroll
    for (int ks = 0; ks < 4; ++ks)
#pragma unroll
      for (int nb = 0; nb < 4; ++nb) {
        int row = nb * 32 + l31;
        int slot = (2 * ks + hh) ^ (row & 7);
        bf16x8 bv = ld16(&VL[cur][row * 64 + slot * 8]);
        o[nb] = MFMA32(pa[ks], bv, o[nb]);
      }
    __builtin_amdgcn_s_setprio(0);
    if (kv < 7) __syncthreads();
  }
  float inv = 1.f / l;
#pragma unroll
  for (int r = 0; r < 16; ++r) {
    int qr = (r & 3) + 8 * (r >> 2) + 4 * hh;
    float iv = __shfl(inv, (ln & 32) | qr, 64);
    int row = q0 + qr;
    u16* dst = O + ((size_t)n * 512 + row) * 2048 + h * 128;
    dst[0 * 32 + l31] = f2bf(o[0][r] * iv);
    dst[1 * 32 + l31] = f2bf(o[1][r] * iv);
    dst[2 * 32 + l31] = f2bf(o[2][r] * iv);
    dst[3 * 32 + l31] = f2bf(o[3][r] * iv);
  }
}

// ---------------- FC GEMM: 128Mx256N, BK=64, 8 waves, 4-phase counted ------
// Grid 256 blocks 1D: bn = blk&7 == XCD (each XCD keeps its 1MB W-panel
// L2-hot and streams A exactly once). 8 waves = 2M x 4N, 64x64/wave.
// Per K-step: P0{stageA2,vmcnt(2),bar,8 MFMA,bar} P1{stageB2,8,bar}
// P2{stageB2,8,bar} P3{8,bar}. Steady state: exactly 6 loads in flight at
// each P0; vmcnt(2) drains precisely the current tile's 6 (never 0 mid-loop).
// XOR swizzle slot^=(row&7) on source + ds_read (rule #21); conflicts = 0.
__global__ __launch_bounds__(512, 1) void fc_kernel(
    const u16* __restrict__ A, const u16* __restrict__ Bw,
    const float* __restrict__ bias, float* __restrict__ doutF,
    u16* __restrict__ doutB, int last, int bsh) {
  __shared__ u16 AL[2][128 * 64];
  __shared__ u16 BL[2][256 * 64];
  int blk = blockIdx.x;
  int bm = blk >> 3, bn = blk & 7;
  int tid = threadIdx.x, wv = tid >> 6, ln = tid & 63;
  int lr = ln & 15, lg = ln >> 4;
  int R0 = bm * 128, C0 = bn * 256;
  int wr = (wv >> 2) * 64, wc = (wv & 3) * 64;
  // staging: per wave A=2 instrs (8 rows each), B=4 instrs
  const u16* gA[2];
  int sA[2];
  const u16* gB[4];
  int sB[4];
#pragma unroll
  for (int i = 0; i < 2; ++i) {
    int r = wv * 16 + i * 8 + (ln >> 3);
    int cs = ((ln & 7) ^ (r & 7)) * 8;
    gA[i] = A + (size_t)(R0 + r) * 2048 + cs;
    sA[i] = (wv * 16 + i * 8) * 64;
  }
#pragma unroll
  for (int i = 0; i < 4; ++i) {
    int r = wv * 32 + i * 8 + (ln >> 3);
    int cs = ((ln & 7) ^ (r & 7)) * 8;
    gB[i] = Bw + (size_t)(C0 + r) * 2048 + cs;
    sB[i] = (wv * 32 + i * 8) * 64;
  }
  // ds_read offsets: row*64 + (slot^(row&7))*8, slot = kk*4+lg
  int aoff[4][2], boff[4][2];
#pragma unroll
  for (int i = 0; i < 4; ++i) {
    int ra = wr + i * 16 + lr, rb = wc + i * 16 + lr;
#pragma unroll
    for (int kk = 0; kk < 2; ++kk) {
      aoff[i][kk] = ra * 64 + (((kk * 4 + lg) ^ (ra & 7)) * 8);
      boff[i][kk] = rb * 64 + (((kk * 4 + lg) ^ (rb & 7)) * 8);
    }
  }
  f32x4 acc[4][4] = {};
  // prologue: stage tile 0 (6 loads in flight)
#pragma unroll
  for (int i = 0; i < 2; ++i) gl_lds(gA[i], &AL[0][sA[i]]);
#pragma unroll
  for (int i = 0; i < 4; ++i) gl_lds(gB[i], &BL[0][sB[i]]);

  for (int t = 0; t < 32; ++t) {
    int cur = t & 1, nx = cur ^ 1;
    int k0 = (t + 1) * 64;
    // ---- P0: stage A(2), counted drain of tile t, MFMA kk0 x m01
    if (t < 31) {
      gl_lds(gA[0] + k0, &AL[nx][sA[0]]);
      gl_lds(gA[1] + k0, &AL[nx][sA[1]]);
      asm volatile("s_waitcnt vmcnt(2)" ::: "memory");
    } else {
      asm volatile("s_waitcnt vmcnt(0)" ::: "memory");
    }
    __builtin_amdgcn_s_barrier();
    bf16x8 b0 = ld16(&BL[cur][boff[0][0]]), b1 = ld16(&BL[cur][boff[1][0]]);
    bf16x8 b2 = ld16(&BL[cur][boff[2][0]]), b3 = ld16(&BL[cur][boff[3][0]]);
    {
      bf16x8 a0 = ld16(&AL[cur][aoff[0][0]]), a1 = ld16(&AL[cur][aoff[1][0]]);
      __builtin_amdgcn_s_setprio(1);
      acc[0][0] = MFMA16(a0, b0, acc[0][0]);
      acc[0][1] = MFMA16(a0, b1, acc[0][1]);
      acc[0][2] = MFMA16(a0, b2, acc[0][2]);
      acc[0][3] = MFMA16(a0, b3, acc[0][3]);
      acc[1][0] = MFMA16(a1, b0, acc[1][0]);
      acc[1][1] = MFMA16(a1, b1, acc[1][1]);
      acc[1][2] = MFMA16(a1, b2, acc[1][2]);
      acc[1][3] = MFMA16(a1, b3, acc[1][3]);
      __builtin_amdgcn_s_setprio(0);
    }
    __builtin_amdgcn_s_barrier();
    // ---- P1: stage B(2), MFMA kk0 x m23
    if (t < 31) {
      gl_lds(gB[0] + k0, &BL[nx][sB[0]]);
      gl_lds(gB[1] + k0, &BL[nx][sB[1]]);
    }
    {
      bf16x8 a2 = ld16(&AL[cur][aoff[2][0]]), a3 = ld16(&AL[cur][aoff[3][0]]);
      __builtin_amdgcn_s_setprio(1);
      acc[2][0] = MFMA16(a2, b0, acc[2][0]);
      acc[2][1] = MFMA16(a2, b1, acc[2][1]);
      acc[2][2] = MFMA16(a2, b2, acc[2][2]);
      acc[2][3] = MFMA16(a2, b3, acc[2][3]);
      acc[3][0] = MFMA16(a3, b0, acc[3][0]);
      acc[3][1] = MFMA16(a3, b1, acc[3][1]);
      acc[3][2] = MFMA16(a3, b2, acc[3][2]);
      acc[3][3] = MFMA16(a3, b3, acc[3][3]);
      __builtin_amdgcn_s_setprio(0);
    }
    __builtin_amdgcn_s_barrier();
    // ---- P2: stage B(2), MFMA kk1 x m01
    if (t < 31) {
      gl_lds(gB[2] + k0, &BL[nx][sB[2]]);
      gl_lds(gB[3] + k0, &BL[nx][sB[3]]);
    }
    b0 = ld16(&BL[cur][boff[0][1]]); b1 = ld16(&BL[cur][boff[1][1]]);
    b2 = ld16(&BL[cur][boff[2][1]]); b3 = ld16(&BL[cur][boff[3][1]]);
    {
      bf16x8 a0 = ld16(&AL[cur][aoff[0][1]]), a1 = ld16(&AL[cur][aoff[1][1]]);
      __builtin_amdgcn_s_setprio(1);
      acc[0][0] = MFMA16(a0, b0, acc[0][0]);
      acc[0][1] = MFMA16(a0, b1, acc[0][1]);
      acc[0][2] = MFMA16(a0, b2, acc[0][2]);
      acc[0][3] = MFMA16(a0, b3, acc[0][3]);
      acc[1][0] = MFMA16(a1, b0, acc[1][0]);
      acc[1][1] = MFMA16(a1, b1, acc[1][1]);
      acc[1][2] = MFMA16(a1, b2, acc[1][2]);
      acc[1][3] = MFMA16(a1, b3, acc[1][3]);
      __builtin_amdgcn_s_setprio(0);
    }
    __builtin_amdgcn_s_barrier();
    // ---- P3: MFMA kk1 x m23
    {
      bf16x8 a2 = ld16(&AL[cur][aoff[2][1]]), a3 = ld16(&AL[cur][aoff[3][1]]);
      __builtin_amdgcn_s_setprio(1);
      acc[2][0] = MFMA16(a2, b0, acc[2][0]);
      acc[2][1] = MFMA16(a2, b1, acc[2][1]);
      acc[2][2] = MFMA16(a2, b2, acc[2][2]);
      acc[2][3] = MFMA16(a2, b3, acc[2][3]);
      acc[3][0] = MFMA16(a3, b0, acc[3][0]);
      acc[3][1] = MFMA16(a3, b1, acc[3][1]);
      acc[3][2] = MFMA16(a3, b2, acc[3][2]);
      acc[3][3] = MFMA16(a3, b3, acc[3][3]);
      __builtin_amdgcn_s_setprio(0);
    }
    __builtin_amdgcn_s_barrier();  // all waves done with buf[cur]
  }
  // epilogue: bias + permuted scatter (bf16 state or f32 final)
#pragma unroll
  for (int nc = 0; nc < 4; ++nc) {
    int e = C0 + wc + nc * 16 + lr;
    float bv = bias[e];
    int i = e >> 8, cc = e & 255;
#pragma unroll
    for (int mt = 0; mt < 4; ++mt)
#pragma unroll
      for (int r = 0; r < 4; ++r) {
        int row = R0 + wr + mt * 16 + lg * 4 + r;
        int nn = row >> 9, j = row & 511;
        int pos = (8 * j + i - bsh) & 4095;
        size_t di = ((size_t)nn * 4096 + pos) * 256 + cc;
        float v = acc[mt][nc][r] + bv;
        if (last) doutF[di] = v;
        else doutB[di] = f2bf(v);
      }
  }
}

extern "C" void kernel_launch(void* const* d_in, const int* in_sizes, int n_in,
                              void* d_out, int out_size, void* d_ws, size_t ws_size,
                              hipStream_t stream) {
  const float* M = (const float*)d_in[0];
  const float* Wq = (const float*)d_in[1];
  const float* Wk = (const float*)d_in[2];
  const float* Wv = (const float*)d_in[3];
  const float* fcw = (const float*)d_in[4];
  const float* fcb = (const float*)d_in[5];
  float* out = (float*)d_out;
  char* ws = (char*)d_ws;
  u16* wq_b = (u16*)(ws + (0 << 10));
  u16* wk_b = (u16*)(ws + (32 << 10));
  u16* wv_b = (u16*)(ws + (64 << 10));
  u16* fcw_b = (u16*)(ws + (128 << 10));
  u16* Qb = (u16*)(ws + ((size_t)16 << 20));
  u16* Kb = (u16*)(ws + ((size_t)32 << 20));
  u16* Vtb = (u16*)(ws + ((size_t)48 << 20));
  u16* Ab = (u16*)(ws + ((size_t)64 << 20));
  u16* Sb = (u16*)(ws + ((size_t)96 << 20));  // bf16 state ping (16.8 MB)

  convert_weights<<<4112, 256, 0, stream>>>(Wq, Wk, Wv, fcw, wq_b, wk_b, wv_b, fcw_b);
  for (int b = 0; b < 8; ++b) {
    qkv_kernel<<<dim3(8, 8, 8), 768, 0, stream>>>(M, Sb, (b == 0) ? 1 : 0,
                                                  wq_b, wk_b, wv_b, Qb, Kb, Vtb, b);
    attn_kernel<<<512, 256, 0, stream>>>(Qb, Kb, Vtb, Ab);
    fc_kernel<<<256, 512, 0, stream>>>(Ab, fcw_b, fcb, out, Sb,
                                       (b == 7) ? 1 : 0, b);
  }
}

// Round 8
// 721.169 us; speedup vs baseline: 1.2429x; 1.2429x over previous
//
#include <hip/hip_runtime.h>
#include <stdint.h>

typedef unsigned short u16;
typedef unsigned int u32;
typedef __bf16 bf16x8 __attribute__((ext_vector_type(8)));
typedef float f32x4 __attribute__((ext_vector_type(4)));
typedef float f32x16 __attribute__((ext_vector_type(16)));
typedef u16 u16x4 __attribute__((ext_vector_type(4)));
typedef u16 u16x8 __attribute__((ext_vector_type(8)));

#define MFMA16(a, b, c) __builtin_amdgcn_mfma_f32_16x16x32_bf16(a, b, c, 0, 0, 0)
#define MFMA32(a, b, c) __builtin_amdgcn_mfma_f32_32x32x16_bf16(a, b, c, 0, 0, 0)

__device__ __forceinline__ u16 f2bf(float f) {
  u32 u = __builtin_bit_cast(u32, f);
  u += 0x7FFFu + ((u >> 16) & 1u);
  return (u16)(u >> 16);
}

__device__ __forceinline__ bf16x8 ld16(const u16* p) {
  return __builtin_bit_cast(bf16x8, *(const uint4*)p);
}

__device__ __forceinline__ void gl_lds(const u16* src, u16* lds) {
  __builtin_amdgcn_global_load_lds(
      (const __attribute__((address_space(1))) u32*)src,
      (__attribute__((address_space(3))) u32*)lds, 16, 0, 0);
}

// ---------------- weight conversion (once per launch) ----------------
__global__ __launch_bounds__(256) void convert_weights(
    const float* __restrict__ Wq, const float* __restrict__ Wk,
    const float* __restrict__ Wv, const float* __restrict__ fcw,
    u16* __restrict__ wq_b, u16* __restrict__ wk_b, u16* __restrict__ wv_b,
    u16* __restrict__ fcw_b) {
  int bx = blockIdx.x, tid = threadIdx.x;
  if (bx < 4096) {
    int i = (bx * 256 + tid) * 4;
    float4 f = *(const float4*)&fcw[i];
    u16x4 o = {f2bf(f.x), f2bf(f.y), f2bf(f.z), f2bf(f.w)};
    *(u16x4*)&fcw_b[i] = o;
  } else {
    int i = ((bx - 4096) * 256 + tid) * 4;
    const float sc = 0.022097086912079612f;  // 1/sqrt(2048) folded into Wq
    float4 q = *(const float4*)&Wq[i];
    u16x4 oq = {f2bf(q.x * sc), f2bf(q.y * sc), f2bf(q.z * sc), f2bf(q.w * sc)};
    *(u16x4*)&wq_b[i] = oq;
    float4 k = *(const float4*)&Wk[i];
    u16x4 ok = {f2bf(k.x), f2bf(k.y), f2bf(k.z), f2bf(k.w)};
    *(u16x4*)&wk_b[i] = ok;
    float4 v = *(const float4*)&Wv[i];
    u16x4 ov = {f2bf(v.x), f2bf(v.y), f2bf(v.z), f2bf(v.w)};
    *(u16x4*)&wv_b[i] = ov;
  }
}

// ---------------- QKV projection, 2 heads per block ----------------
__global__ __launch_bounds__(768) void qkv_kernel(
    const float* __restrict__ srcF, const u16* __restrict__ srcB, int srcf32,
    const u16* __restrict__ wq, const u16* __restrict__ wk,
    const u16* __restrict__ wvw, u16* __restrict__ Q, u16* __restrict__ K,
    u16* __restrict__ Vt, int bsh) {
  __shared__ u16 X[64 * 264];
  int jt = blockIdx.x, i0 = blockIdx.y, n = blockIdx.z;
  int tid = threadIdx.x;
#pragma unroll
  for (int it = 0; it < 3; ++it) {
    int c = tid + it * 768;
    if (c < 2048) {
      int row = c >> 5, seg = c & 31;
      int pos = (8 * (jt * 64 + row) + i0 - bsh) & 4095;
      size_t base = ((size_t)n * 4096 + pos) * 256 + seg * 8;
      if (srcf32) {
        float4 f0 = *(const float4*)&srcF[base];
        float4 f1 = *(const float4*)&srcF[base + 4];
        u16x8 v = {f2bf(f0.x), f2bf(f0.y), f2bf(f0.z), f2bf(f0.w),
                   f2bf(f1.x), f2bf(f1.y), f2bf(f1.z), f2bf(f1.w)};
        *(u16x8*)&X[row * 264 + seg * 8] = v;
      } else {
        *(u16x8*)&X[row * 264 + seg * 8] = *(const u16x8*)&srcB[base];
      }
    }
  }
  __syncthreads();
  int wvid = tid >> 6, ln = tid & 63;
  int mat = wvid >> 2, hc = wvid & 3;
  int hh = hc >> 1, cb = (hc & 1) * 64;
  int h = i0 * 2 + hh, xc = hh * 128;
  const u16* W = (mat == 0) ? wq : (mat == 1) ? wk : wvw;
  int lr = ln & 15, lg = ln >> 4;
  f32x4 acc[4][4] = {};
#pragma unroll
  for (int kt = 0; kt < 4; ++kt) {
    bf16x8 a[4], b[4];
#pragma unroll
    for (int mt = 0; mt < 4; ++mt)
      a[mt] = ld16(&X[(mt * 16 + lr) * 264 + xc + kt * 32 + lg * 8]);
#pragma unroll
    for (int nc = 0; nc < 4; ++nc)
      b[nc] = ld16(&W[(cb + nc * 16 + lr) * 128 + kt * 32 + lg * 8]);
#pragma unroll
    for (int mt = 0; mt < 4; ++mt)
#pragma unroll
      for (int nc = 0; nc < 4; ++nc)
        acc[mt][nc] = MFMA16(a[mt], b[nc], acc[mt][nc]);
  }
  size_t nh = (size_t)(n * 16 + h);
  if (mat < 2) {
    u16* dst = (mat == 0 ? Q : K) + nh * 512 * 128;
#pragma unroll
    for (int mt = 0; mt < 4; ++mt)
#pragma unroll
      for (int nc = 0; nc < 4; ++nc) {
        int col = cb + nc * 16 + lr;
        int jb = jt * 64 + mt * 16 + lg * 4;
#pragma unroll
        for (int r = 0; r < 4; ++r)
          dst[(size_t)(jb + r) * 128 + col] = f2bf(acc[mt][nc][r]);
      }
  } else {
    u16* dst = Vt + nh * 128 * 512;
#pragma unroll
    for (int mt = 0; mt < 4; ++mt)
#pragma unroll
      for (int nc = 0; nc < 4; ++nc) {
        int col = cb + nc * 16 + lr;
        int jb = jt * 64 + mt * 16 + lg * 4;
        u16x4 pk = {f2bf(acc[mt][nc][0]), f2bf(acc[mt][nc][1]),
                    f2bf(acc[mt][nc][2]), f2bf(acc[mt][nc][3])};
        *(u16x4*)&dst[(size_t)col * 512 + jb] = pk;
      }
  }
}

// ---------------- flash attention: T15 att[2] pipeline ----------------
// K triple-buffered (staged 2 ahead), V double-buffered (staged 1 ahead).
// QK^T(t+1) is issued before softmax(t): independent MFMA vs VALU work that
// the scheduler interleaves (m214 v36 mechanism). All buffer indices are
// compile-time (full unroll, rule #20). End-of-iter __syncthreads (implicit
// vmcnt(0)) guarantees every staged buffer before its first reader; every
// overwritten buffer was last read before the previous barrier.
__global__ __launch_bounds__(256, 2) void attn_kernel(
    const u16* __restrict__ Q, const u16* __restrict__ K,
    const u16* __restrict__ Vt, u16* __restrict__ O) {
  __shared__ u16 KL[3][64 * 128];
  __shared__ u16 VL[2][128 * 64];
  int flat = blockIdx.x;
  int xcd = flat & 7, idx = flat >> 3;
  int gl = idx & 15, qt = idx >> 4;
  int g = xcd | (gl << 3);
  int h = g & 15, n = g >> 4;
  int tid = threadIdx.x, wv = tid >> 6, ln = tid & 63;
  int l31 = ln & 31, hh = ln >> 5;
  size_t nh = (size_t)(n * 16 + h);
  int q0 = qt * 128 + wv * 32;
  const u16* Qb = Q + ((size_t)nh * 512 + q0) * 128;
  const u16* Kb = K + (size_t)nh * 512 * 128;
  const u16* Vb = Vt + (size_t)nh * 128 * 512;

  bf16x8 qf[8];
#pragma unroll
  for (int kt = 0; kt < 8; ++kt)
    qf[kt] = ld16(&Qb[l31 * 128 + kt * 16 + hh * 8]);

  // per-wave staging geometry (source-side XOR swizzle, rule #21)
  int l16 = ln & 15, l8 = ln & 7;
  int rK[4], cK[4], rV[4], cV[4];
#pragma unroll
  for (int i = 0; i < 4; ++i) {
    int s = wv * 4 + i;
    rK[i] = 4 * s + (ln >> 4);
    cK[i] = (l16 ^ (rK[i] & 15)) * 8;
    rV[i] = 8 * s + (ln >> 3);
    cV[i] = (l8 ^ (rV[i] & 7)) * 8;
  }

#define STAGE_K(buf, kv)                                                     \
  {                                                                          \
    const u16* kp_ = Kb + (size_t)(kv) * 64 * 128;                           \
    _Pragma("unroll") for (int i_ = 0; i_ < 4; ++i_) {                       \
      int s_ = wv * 4 + i_;                                                  \
      gl_lds(&kp_[(size_t)rK[i_] * 128 + cK[i_]], &KL[buf][s_ * 512]);       \
    }                                                                        \
  }
#define STAGE_V(buf, kv)                                                     \
  {                                                                          \
    _Pragma("unroll") for (int i_ = 0; i_ < 4; ++i_) {                       \
      int s_ = wv * 4 + i_;                                                  \
      gl_lds(&Vb[(size_t)rV[i_] * 512 + (kv)*64 + cV[i_]], &VL[buf][s_ * 512]); \
    }                                                                        \
  }

  // prologue: K0, V0, K1 staged; then QK(0) -> ps[0]
  STAGE_K(0, 0);
  STAGE_V(0, 0);
  STAGE_K(1, 1);
  __syncthreads();

  f32x16 ps[2][2];
  f32x16 o[4] = {};
  float m = -1e30f, l = 0.f;

  // QK(0)
  {
    f32x16 z = {};
    ps[0][0] = z; ps[0][1] = z;
#pragma unroll
    for (int kt = 0; kt < 8; ++kt) {
      int slot0 = (2 * kt + hh) ^ (l31 & 15);
      bf16x8 a0 = ld16(&KL[0][l31 * 128 + slot0 * 8]);
      ps[0][0] = MFMA32(a0, qf[kt], ps[0][0]);
      int row1 = 32 + l31;
      int slot1 = (2 * kt + hh) ^ (row1 & 15);
      bf16x8 a1 = ld16(&KL[0][row1 * 128 + slot1 * 8]);
      ps[0][1] = MFMA32(a1, qf[kt], ps[0][1]);
    }
  }

#pragma unroll
  for (int t = 0; t < 8; ++t) {
    const int cur = t & 1, nxt = (t + 1) & 1;
    // stage K(t+2), V(t+1)
    if (t + 2 <= 7) STAGE_K((t + 2) % 3, t + 2);
    if (t + 1 <= 7) STAGE_V(nxt, t + 1);
    // QK(t+1) -> ps[nxt]  (independent of SM(t): interleaves with VALU below)
    if (t + 1 <= 7) {
      const int kb = (t + 1) % 3;
      f32x16 z = {};
      ps[nxt][0] = z; ps[nxt][1] = z;
#pragma unroll
      for (int kt = 0; kt < 8; ++kt) {
        int slot0 = (2 * kt + hh) ^ (l31 & 15);
        bf16x8 a0 = ld16(&KL[kb][l31 * 128 + slot0 * 8]);
        ps[nxt][0] = MFMA32(a0, qf[kt], ps[nxt][0]);
        int row1 = 32 + l31;
        int slot1 = (2 * kt + hh) ^ (row1 & 15);
        bf16x8 a1 = ld16(&KL[kb][row1 * 128 + slot1 * 8]);
        ps[nxt][1] = MFMA32(a1, qf[kt], ps[nxt][1]);
      }
    }
    // ---- softmax(t) on ps[cur] ----
    float mx[8];
#pragma unroll
    for (int i = 0; i < 8; ++i)
      mx[i] = fmaxf(fmaxf(ps[cur][0][2 * i], ps[cur][0][2 * i + 1]),
                    fmaxf(ps[cur][1][2 * i], ps[cur][1][2 * i + 1]));
    float pm = fmaxf(fmaxf(fmaxf(mx[0], mx[1]), fmaxf(mx[2], mx[3])),
                     fmaxf(fmaxf(mx[4], mx[5]), fmaxf(mx[6], mx[7])));
    pm = fmaxf(pm, __shfl_xor(pm, 32));
    if (!__all(pm <= m + 8.f)) {
      float nm = fmaxf(m, pm);
      float al = __expf(m - nm);
      l *= al;
      m = nm;
#pragma unroll
      for (int r = 0; r < 16; ++r) {
        int qr = (r & 3) + 8 * (r >> 2) + 4 * hh;
        float av = __shfl(al, (ln & 32) | qr, 64);
        o[0][r] *= av; o[1][r] *= av; o[2][r] *= av; o[3][r] *= av;
      }
    }
#pragma unroll
    for (int kb2 = 0; kb2 < 2; ++kb2)
#pragma unroll
      for (int r = 0; r < 16; ++r)
        ps[cur][kb2][r] = __expf(ps[cur][kb2][r] - m);
    float sm[8];
#pragma unroll
    for (int i = 0; i < 8; ++i)
      sm[i] = (ps[cur][0][2 * i] + ps[cur][0][2 * i + 1]) +
              (ps[cur][1][2 * i] + ps[cur][1][2 * i + 1]);
    float rs = ((sm[0] + sm[1]) + (sm[2] + sm[3])) +
               ((sm[4] + sm[5]) + (sm[6] + sm[7]));
    rs += __shfl_xor(rs, 32);
    l += rs;
    // P -> A-frags in-register (T12)
    bf16x8 pa[4];
#pragma unroll
    for (int ks = 0; ks < 4; ++ks) {
      const int kb2 = ks >> 1, r0 = 8 * (ks & 1);
      u32 wA, wB, wC, wD;
      asm("v_cvt_pk_bf16_f32 %0, %1, %2" : "=v"(wA) : "v"(ps[cur][kb2][r0 + 0]), "v"(ps[cur][kb2][r0 + 1]));
      asm("v_cvt_pk_bf16_f32 %0, %1, %2" : "=v"(wB) : "v"(ps[cur][kb2][r0 + 2]), "v"(ps[cur][kb2][r0 + 3]));
      asm("v_cvt_pk_bf16_f32 %0, %1, %2" : "=v"(wC) : "v"(ps[cur][kb2][r0 + 4]), "v"(ps[cur][kb2][r0 + 5]));
      asm("v_cvt_pk_bf16_f32 %0, %1, %2" : "=v"(wD) : "v"(ps[cur][kb2][r0 + 6]), "v"(ps[cur][kb2][r0 + 7]));
      asm("v_permlane32_swap_b32 %0, %1" : "+v"(wA), "+v"(wC));
      asm("v_permlane32_swap_b32 %0, %1" : "+v"(wB), "+v"(wD));
      uint4 ww = {wA, wB, wC, wD};
      pa[ks] = __builtin_bit_cast(bf16x8, ww);
    }
    // ---- PV(t) from VL[cur] ----
    __builtin_amdgcn_s_setprio(1);
#pragma unroll
    for (int ks = 0; ks < 4; ++ks)
#pragma unroll
      for (int nb = 0; nb < 4; ++nb) {
        int row = nb * 32 + l31;
        int slot = (2 * ks + hh) ^ (row & 7);
        bf16x8 bv = ld16(&VL[cur][row * 64 + slot * 8]);
        o[nb] = MFMA32(pa[ks], bv, o[nb]);
      }
    __builtin_amdgcn_s_setprio(0);
    if (t < 7) __syncthreads();
  }
#undef STAGE_K
#undef STAGE_V

  float inv = 1.f / l;
#pragma unroll
  for (int r = 0; r < 16; ++r) {
    int qr = (r & 3) + 8 * (r >> 2) + 4 * hh;
    float iv = __shfl(inv, (ln & 32) | qr, 64);
    int row = q0 + qr;
    u16* dst = O + ((size_t)n * 512 + row) * 2048 + h * 128;
    dst[0 * 32 + l31] = f2bf(o[0][r] * iv);
    dst[1 * 32 + l31] = f2bf(o[1][r] * iv);
    dst[2 * 32 + l31] = f2bf(o[2][r] * iv);
    dst[3 * 32 + l31] = f2bf(o[3][r] * iv);
  }
}

// ---------------- FC GEMM: 128x128 tile, BK=64, dbuf + counted vmcnt -------
// (exact R6 structure: 792 TF known-good)
__global__ __launch_bounds__(256, 2) void fc_kernel(
    const u16* __restrict__ A, const u16* __restrict__ Bw,
    const float* __restrict__ bias, float* __restrict__ doutF,
    u16* __restrict__ doutB, int last, int bsh) {
  __shared__ u16 AL[2][128 * 64];
  __shared__ u16 BL[2][128 * 64];
  int bn = blockIdx.x, bm = blockIdx.y;
  int tid = threadIdx.x, wv = tid >> 6, ln = tid & 63;
  int lr = ln & 15, lg = ln >> 4;
  int R0 = bm * 128, C0 = bn * 128;
  int wr = (wv & 1) * 64, wc = (wv >> 1) * 64;
  const u16 *gAsrc[4], *gBsrc[4];
  int srow[4];
#pragma unroll
  for (int i = 0; i < 4; ++i) {
    int r = i * 32 + wv * 8 + (ln >> 3);
    int cs = ((ln & 7) ^ (r & 7)) * 8;
    gAsrc[i] = A + (size_t)(R0 + r) * 2048 + cs;
    gBsrc[i] = Bw + (size_t)(C0 + r) * 2048 + cs;
    srow[i] = i * 32 + wv * 8;
  }
  int aoff[4][2], boff[4][2];
#pragma unroll
  for (int i = 0; i < 4; ++i) {
    int ra = wr + i * 16 + lr, rb = wc + i * 16 + lr;
#pragma unroll
    for (int kk = 0; kk < 2; ++kk) {
      aoff[i][kk] = ra * 64 + (((kk * 4 + lg) ^ (ra & 7)) * 8);
      boff[i][kk] = rb * 64 + (((kk * 4 + lg) ^ (rb & 7)) * 8);
    }
  }
  f32x4 acc[4][4] = {};
#pragma unroll
  for (int i = 0; i < 4; ++i) {
    gl_lds(gAsrc[i], &AL[0][srow[i] * 64]);
    gl_lds(gBsrc[i], &BL[0][srow[i] * 64]);
  }
  for (int t = 0; t < 32; ++t) {
    int cur = t & 1, nx = cur ^ 1;
    if (t < 31) {
      int k0 = (t + 1) * 64;
#pragma unroll
      for (int i = 0; i < 4; ++i) {
        gl_lds(gAsrc[i] + k0, &AL[nx][srow[i] * 64]);
        gl_lds(gBsrc[i] + k0, &BL[nx][srow[i] * 64]);
      }
      asm volatile("s_waitcnt vmcnt(8)" ::: "memory");
    } else {
      asm volatile("s_waitcnt vmcnt(0)" ::: "memory");
    }
    __builtin_amdgcn_s_barrier();
#pragma unroll
    for (int kk = 0; kk < 2; ++kk) {
      bf16x8 a[4], b[4];
#pragma unroll
      for (int i = 0; i < 4; ++i) a[i] = ld16(&AL[cur][aoff[i][kk]]);
#pragma unroll
      for (int i = 0; i < 4; ++i) b[i] = ld16(&BL[cur][boff[i][kk]]);
      __builtin_amdgcn_s_setprio(1);
#pragma unroll
      for (int mt = 0; mt < 4; ++mt)
#pragma unroll
        for (int nc = 0; nc < 4; ++nc)
          acc[mt][nc] = MFMA16(a[mt], b[nc], acc[mt][nc]);
      __builtin_amdgcn_s_setprio(0);
    }
    if (t < 31) __builtin_amdgcn_s_barrier();
  }
#pragma unroll
  for (int nc = 0; nc < 4; ++nc) {
    int e = C0 + wc + nc * 16 + lr;
    float bv = bias[e];
    int i = e >> 8, cc = e & 255;
#pragma unroll
    for (int mt = 0; mt < 4; ++mt)
#pragma unroll
      for (int r = 0; r < 4; ++r) {
        int row = R0 + wr + mt * 16 + lg * 4 + r;
        int nn = row >> 9, j = row & 511;
        int pos = (8 * j + i - bsh) & 4095;
        size_t di = ((size_t)nn * 4096 + pos) * 256 + cc;
        float v = acc[mt][nc][r] + bv;
        if (last) doutF[di] = v;
        else doutB[di] = f2bf(v);
      }
  }
}

extern "C" void kernel_launch(void* const* d_in, const int* in_sizes, int n_in,
                              void* d_out, int out_size, void* d_ws, size_t ws_size,
                              hipStream_t stream) {
  const float* M = (const float*)d_in[0];
  const float* Wq = (const float*)d_in[1];
  const float* Wk = (const float*)d_in[2];
  const float* Wv = (const float*)d_in[3];
  const float* fcw = (const float*)d_in[4];
  const float* fcb = (const float*)d_in[5];
  float* out = (float*)d_out;
  char* ws = (char*)d_ws;
  u16* wq_b = (u16*)(ws + (0 << 10));
  u16* wk_b = (u16*)(ws + (32 << 10));
  u16* wv_b = (u16*)(ws + (64 << 10));
  u16* fcw_b = (u16*)(ws + (128 << 10));
  u16* Qb = (u16*)(ws + ((size_t)16 << 20));
  u16* Kb = (u16*)(ws + ((size_t)32 << 20));
  u16* Vtb = (u16*)(ws + ((size_t)48 << 20));
  u16* Ab = (u16*)(ws + ((size_t)64 << 20));
  u16* Sb = (u16*)(ws + ((size_t)96 << 20));  // bf16 state ping (16.8 MB)

  convert_weights<<<4112, 256, 0, stream>>>(Wq, Wk, Wv, fcw, wq_b, wk_b, wv_b, fcw_b);
  for (int b = 0; b < 8; ++b) {
    qkv_kernel<<<dim3(8, 8, 8), 768, 0, stream>>>(M, Sb, (b == 0) ? 1 : 0,
                                                  wq_b, wk_b, wv_b, Qb, Kb, Vtb, b);
    attn_kernel<<<512, 256, 0, stream>>>(Qb, Kb, Vtb, Ab);
    fc_kernel<<<dim3(16, 32), 256, 0, stream>>>(Ab, fcw_b, fcb, out, Sb,
                                                (b == 7) ? 1 : 0, b);
  }
}

// Round 9
// 714.050 us; speedup vs baseline: 1.2553x; 1.0100x over previous
//
#include <hip/hip_runtime.h>
#include <stdint.h>

typedef unsigned short u16;
typedef unsigned int u32;
typedef __bf16 bf16x8 __attribute__((ext_vector_type(8)));
typedef float f32x4 __attribute__((ext_vector_type(4)));
typedef float f32x16 __attribute__((ext_vector_type(16)));
typedef u16 u16x4 __attribute__((ext_vector_type(4)));
typedef u16 u16x8 __attribute__((ext_vector_type(8)));

#define MFMA16(a, b, c) __builtin_amdgcn_mfma_f32_16x16x32_bf16(a, b, c, 0, 0, 0)
#define MFMA32(a, b, c) __builtin_amdgcn_mfma_f32_32x32x16_bf16(a, b, c, 0, 0, 0)

__device__ __forceinline__ u16 f2bf(float f) {
  u32 u = __builtin_bit_cast(u32, f);
  u += 0x7FFFu + ((u >> 16) & 1u);
  return (u16)(u >> 16);
}

__device__ __forceinline__ bf16x8 ld16(const u16* p) {
  return __builtin_bit_cast(bf16x8, *(const uint4*)p);
}

__device__ __forceinline__ void gl_lds(const u16* src, u16* lds) {
  __builtin_amdgcn_global_load_lds(
      (const __attribute__((address_space(1))) u32*)src,
      (__attribute__((address_space(3))) u32*)lds, 16, 0, 0);
}

// ---------------- weight conversion (once per launch) ----------------
__global__ __launch_bounds__(256) void convert_weights(
    const float* __restrict__ Wq, const float* __restrict__ Wk,
    const float* __restrict__ Wv, const float* __restrict__ fcw,
    u16* __restrict__ wq_b, u16* __restrict__ wk_b, u16* __restrict__ wv_b,
    u16* __restrict__ fcw_b) {
  int bx = blockIdx.x, tid = threadIdx.x;
  if (bx < 4096) {
    int i = (bx * 256 + tid) * 4;
    float4 f = *(const float4*)&fcw[i];
    u16x4 o = {f2bf(f.x), f2bf(f.y), f2bf(f.z), f2bf(f.w)};
    *(u16x4*)&fcw_b[i] = o;
  } else {
    int i = ((bx - 4096) * 256 + tid) * 4;
    const float sc = 0.022097086912079612f;  // 1/sqrt(2048) folded into Wq
    float4 q = *(const float4*)&Wq[i];
    u16x4 oq = {f2bf(q.x * sc), f2bf(q.y * sc), f2bf(q.z * sc), f2bf(q.w * sc)};
    *(u16x4*)&wq_b[i] = oq;
    float4 k = *(const float4*)&Wk[i];
    u16x4 ok = {f2bf(k.x), f2bf(k.y), f2bf(k.z), f2bf(k.w)};
    *(u16x4*)&wk_b[i] = ok;
    float4 v = *(const float4*)&Wv[i];
    u16x4 ov = {f2bf(v.x), f2bf(v.y), f2bf(v.z), f2bf(v.w)};
    *(u16x4*)&wv_b[i] = ov;
  }
}

// ---------------- QKV projection, 2 heads per block ----------------
__global__ __launch_bounds__(768) void qkv_kernel(
    const float* __restrict__ srcF, const u16* __restrict__ srcB, int srcf32,
    const u16* __restrict__ wq, const u16* __restrict__ wk,
    const u16* __restrict__ wvw, u16* __restrict__ Q, u16* __restrict__ K,
    u16* __restrict__ Vt, int bsh) {
  __shared__ u16 X[64 * 264];
  int jt = blockIdx.x, i0 = blockIdx.y, n = blockIdx.z;
  int tid = threadIdx.x;
#pragma unroll
  for (int it = 0; it < 3; ++it) {
    int c = tid + it * 768;
    if (c < 2048) {
      int row = c >> 5, seg = c & 31;
      int pos = (8 * (jt * 64 + row) + i0 - bsh) & 4095;
      size_t base = ((size_t)n * 4096 + pos) * 256 + seg * 8;
      if (srcf32) {
        float4 f0 = *(const float4*)&srcF[base];
        float4 f1 = *(const float4*)&srcF[base + 4];
        u16x8 v = {f2bf(f0.x), f2bf(f0.y), f2bf(f0.z), f2bf(f0.w),
                   f2bf(f1.x), f2bf(f1.y), f2bf(f1.z), f2bf(f1.w)};
        *(u16x8*)&X[row * 264 + seg * 8] = v;
      } else {
        *(u16x8*)&X[row * 264 + seg * 8] = *(const u16x8*)&srcB[base];
      }
    }
  }
  __syncthreads();
  int wvid = tid >> 6, ln = tid & 63;
  int mat = wvid >> 2, hc = wvid & 3;
  int hh = hc >> 1, cb = (hc & 1) * 64;
  int h = i0 * 2 + hh, xc = hh * 128;
  const u16* W = (mat == 0) ? wq : (mat == 1) ? wk : wvw;
  int lr = ln & 15, lg = ln >> 4;
  f32x4 acc[4][4] = {};
#pragma unroll
  for (int kt = 0; kt < 4; ++kt) {
    bf16x8 a[4], b[4];
#pragma unroll
    for (int mt = 0; mt < 4; ++mt)
      a[mt] = ld16(&X[(mt * 16 + lr) * 264 + xc + kt * 32 + lg * 8]);
#pragma unroll
    for (int nc = 0; nc < 4; ++nc)
      b[nc] = ld16(&W[(cb + nc * 16 + lr) * 128 + kt * 32 + lg * 8]);
#pragma unroll
    for (int mt = 0; mt < 4; ++mt)
#pragma unroll
      for (int nc = 0; nc < 4; ++nc)
        acc[mt][nc] = MFMA16(a[mt], b[nc], acc[mt][nc]);
  }
  size_t nh = (size_t)(n * 16 + h);
  if (mat < 2) {
    u16* dst = (mat == 0 ? Q : K) + nh * 512 * 128;
#pragma unroll
    for (int mt = 0; mt < 4; ++mt)
#pragma unroll
      for (int nc = 0; nc < 4; ++nc) {
        int col = cb + nc * 16 + lr;
        int jb = jt * 64 + mt * 16 + lg * 4;
#pragma unroll
        for (int r = 0; r < 4; ++r)
          dst[(size_t)(jb + r) * 128 + col] = f2bf(acc[mt][nc][r]);
      }
  } else {
    u16* dst = Vt + nh * 128 * 512;
#pragma unroll
    for (int mt = 0; mt < 4; ++mt)
#pragma unroll
      for (int nc = 0; nc < 4; ++nc) {
        int col = cb + nc * 16 + lr;
        int jb = jt * 64 + mt * 16 + lg * 4;
        u16x4 pk = {f2bf(acc[mt][nc][0]), f2bf(acc[mt][nc][1]),
                    f2bf(acc[mt][nc][2]), f2bf(acc[mt][nc][3])};
        *(u16x4*)&dst[(size_t)col * 512 + jb] = pk;
      }
  }
}

// ---------------- flash attention: T15 att[2] pipeline (R8, kept) --------
__global__ __launch_bounds__(256, 2) void attn_kernel(
    const u16* __restrict__ Q, const u16* __restrict__ K,
    const u16* __restrict__ Vt, u16* __restrict__ O) {
  __shared__ u16 KL[3][64 * 128];
  __shared__ u16 VL[2][128 * 64];
  int flat = blockIdx.x;
  int xcd = flat & 7, idx = flat >> 3;
  int gl = idx & 15, qt = idx >> 4;
  int g = xcd | (gl << 3);
  int h = g & 15, n = g >> 4;
  int tid = threadIdx.x, wv = tid >> 6, ln = tid & 63;
  int l31 = ln & 31, hh = ln >> 5;
  size_t nh = (size_t)(n * 16 + h);
  int q0 = qt * 128 + wv * 32;
  const u16* Qb = Q + ((size_t)nh * 512 + q0) * 128;
  const u16* Kb = K + (size_t)nh * 512 * 128;
  const u16* Vb = Vt + (size_t)nh * 128 * 512;

  bf16x8 qf[8];
#pragma unroll
  for (int kt = 0; kt < 8; ++kt)
    qf[kt] = ld16(&Qb[l31 * 128 + kt * 16 + hh * 8]);

  int l16 = ln & 15, l8 = ln & 7;
  int rK[4], cK[4], rV[4], cV[4];
#pragma unroll
  for (int i = 0; i < 4; ++i) {
    int s = wv * 4 + i;
    rK[i] = 4 * s + (ln >> 4);
    cK[i] = (l16 ^ (rK[i] & 15)) * 8;
    rV[i] = 8 * s + (ln >> 3);
    cV[i] = (l8 ^ (rV[i] & 7)) * 8;
  }

#define STAGE_K(buf, kv)                                                     \
  {                                                                          \
    const u16* kp_ = Kb + (size_t)(kv) * 64 * 128;                           \
    _Pragma("unroll") for (int i_ = 0; i_ < 4; ++i_) {                       \
      int s_ = wv * 4 + i_;                                                  \
      gl_lds(&kp_[(size_t)rK[i_] * 128 + cK[i_]], &KL[buf][s_ * 512]);       \
    }                                                                        \
  }
#define STAGE_V(buf, kv)                                                     \
  {                                                                          \
    _Pragma("unroll") for (int i_ = 0; i_ < 4; ++i_) {                       \
      int s_ = wv * 4 + i_;                                                  \
      gl_lds(&Vb[(size_t)rV[i_] * 512 + (kv)*64 + cV[i_]], &VL[buf][s_ * 512]); \
    }                                                                        \
  }

  STAGE_K(0, 0);
  STAGE_V(0, 0);
  STAGE_K(1, 1);
  __syncthreads();

  f32x16 ps[2][2];
  f32x16 o[4] = {};
  float m = -1e30f, l = 0.f;

  {
    f32x16 z = {};
    ps[0][0] = z; ps[0][1] = z;
#pragma unroll
    for (int kt = 0; kt < 8; ++kt) {
      int slot0 = (2 * kt + hh) ^ (l31 & 15);
      bf16x8 a0 = ld16(&KL[0][l31 * 128 + slot0 * 8]);
      ps[0][0] = MFMA32(a0, qf[kt], ps[0][0]);
      int row1 = 32 + l31;
      int slot1 = (2 * kt + hh) ^ (row1 & 15);
      bf16x8 a1 = ld16(&KL[0][row1 * 128 + slot1 * 8]);
      ps[0][1] = MFMA32(a1, qf[kt], ps[0][1]);
    }
  }

#pragma unroll
  for (int t = 0; t < 8; ++t) {
    const int cur = t & 1, nxt = (t + 1) & 1;
    if (t + 2 <= 7) STAGE_K((t + 2) % 3, t + 2);
    if (t + 1 <= 7) STAGE_V(nxt, t + 1);
    if (t + 1 <= 7) {
      const int kb = (t + 1) % 3;
      f32x16 z = {};
      ps[nxt][0] = z; ps[nxt][1] = z;
#pragma unroll
      for (int kt = 0; kt < 8; ++kt) {
        int slot0 = (2 * kt + hh) ^ (l31 & 15);
        bf16x8 a0 = ld16(&KL[kb][l31 * 128 + slot0 * 8]);
        ps[nxt][0] = MFMA32(a0, qf[kt], ps[nxt][0]);
        int row1 = 32 + l31;
        int slot1 = (2 * kt + hh) ^ (row1 & 15);
        bf16x8 a1 = ld16(&KL[kb][row1 * 128 + slot1 * 8]);
        ps[nxt][1] = MFMA32(a1, qf[kt], ps[nxt][1]);
      }
    }
    float mx[8];
#pragma unroll
    for (int i = 0; i < 8; ++i)
      mx[i] = fmaxf(fmaxf(ps[cur][0][2 * i], ps[cur][0][2 * i + 1]),
                    fmaxf(ps[cur][1][2 * i], ps[cur][1][2 * i + 1]));
    float pm = fmaxf(fmaxf(fmaxf(mx[0], mx[1]), fmaxf(mx[2], mx[3])),
                     fmaxf(fmaxf(mx[4], mx[5]), fmaxf(mx[6], mx[7])));
    pm = fmaxf(pm, __shfl_xor(pm, 32));
    if (!__all(pm <= m + 8.f)) {
      float nm = fmaxf(m, pm);
      float al = __expf(m - nm);
      l *= al;
      m = nm;
#pragma unroll
      for (int r = 0; r < 16; ++r) {
        int qr = (r & 3) + 8 * (r >> 2) + 4 * hh;
        float av = __shfl(al, (ln & 32) | qr, 64);
        o[0][r] *= av; o[1][r] *= av; o[2][r] *= av; o[3][r] *= av;
      }
    }
#pragma unroll
    for (int kb2 = 0; kb2 < 2; ++kb2)
#pragma unroll
      for (int r = 0; r < 16; ++r)
        ps[cur][kb2][r] = __expf(ps[cur][kb2][r] - m);
    float sm[8];
#pragma unroll
    for (int i = 0; i < 8; ++i)
      sm[i] = (ps[cur][0][2 * i] + ps[cur][0][2 * i + 1]) +
              (ps[cur][1][2 * i] + ps[cur][1][2 * i + 1]);
    float rs = ((sm[0] + sm[1]) + (sm[2] + sm[3])) +
               ((sm[4] + sm[5]) + (sm[6] + sm[7]));
    rs += __shfl_xor(rs, 32);
    l += rs;
    bf16x8 pa[4];
#pragma unroll
    for (int ks = 0; ks < 4; ++ks) {
      const int kb2 = ks >> 1, r0 = 8 * (ks & 1);
      u32 wA, wB, wC, wD;
      asm("v_cvt_pk_bf16_f32 %0, %1, %2" : "=v"(wA) : "v"(ps[cur][kb2][r0 + 0]), "v"(ps[cur][kb2][r0 + 1]));
      asm("v_cvt_pk_bf16_f32 %0, %1, %2" : "=v"(wB) : "v"(ps[cur][kb2][r0 + 2]), "v"(ps[cur][kb2][r0 + 3]));
      asm("v_cvt_pk_bf16_f32 %0, %1, %2" : "=v"(wC) : "v"(ps[cur][kb2][r0 + 4]), "v"(ps[cur][kb2][r0 + 5]));
      asm("v_cvt_pk_bf16_f32 %0, %1, %2" : "=v"(wD) : "v"(ps[cur][kb2][r0 + 6]), "v"(ps[cur][kb2][r0 + 7]));
      asm("v_permlane32_swap_b32 %0, %1" : "+v"(wA), "+v"(wC));
      asm("v_permlane32_swap_b32 %0, %1" : "+v"(wB), "+v"(wD));
      uint4 ww = {wA, wB, wC, wD};
      pa[ks] = __builtin_bit_cast(bf16x8, ww);
    }
    __builtin_amdgcn_s_setprio(1);
#pragma unroll
    for (int ks = 0; ks < 4; ++ks)
#pragma unroll
      for (int nb = 0; nb < 4; ++nb) {
        int row = nb * 32 + l31;
        int slot = (2 * ks + hh) ^ (row & 7);
        bf16x8 bv = ld16(&VL[cur][row * 64 + slot * 8]);
        o[nb] = MFMA32(pa[ks], bv, o[nb]);
      }
    __builtin_amdgcn_s_setprio(0);
    if (t < 7) __syncthreads();
  }
#undef STAGE_K
#undef STAGE_V

  float inv = 1.f / l;
#pragma unroll
  for (int r = 0; r < 16; ++r) {
    int qr = (r & 3) + 8 * (r >> 2) + 4 * hh;
    float iv = __shfl(inv, (ln & 32) | qr, 64);
    int row = q0 + qr;
    u16* dst = O + ((size_t)n * 512 + row) * 2048 + h * 128;
    dst[0 * 32 + l31] = f2bf(o[0][r] * iv);
    dst[1 * 32 + l31] = f2bf(o[1][r] * iv);
    dst[2 * 32 + l31] = f2bf(o[2][r] * iv);
    dst[3 * 32 + l31] = f2bf(o[3][r] * iv);
  }
}

// ---------------- FC GEMM v3: 256Mx128N, BK=64, triple-buf, m201 phases ---
// 256 blocks (1/CU), 8 waves (4M x 2N, 64x64/wave), LDS 144 KB (3 bufs).
// Per K-tile: 2 phases x {8 ds_read (pre-barrier, overlap prev MFMA) ||
// 3 gl_lds stage(t+2) -> s_barrier -> lgkmcnt(0)+sched_barrier ->
// setprio(1) 16 MFMA setprio(0) -> s_barrier}. vmcnt(6) once per K-tile
// (ph1) validates tile t+1 while t+2's 6 loads stay in flight; never 0
// mid-loop. XOR swizzle slot^=(row&7) both sides (rule #21).
__global__ __launch_bounds__(512, 1) void fc_kernel(
    const u16* __restrict__ A, const u16* __restrict__ Bw,
    const float* __restrict__ bias, float* __restrict__ doutF,
    u16* __restrict__ doutB, int last, int bsh) {
  __shared__ u16 AL[3][256 * 64];
  __shared__ u16 BL[3][128 * 64];
  int blk = blockIdx.x;
  int xcd = blk & 7, j = blk >> 3;
  int bn = xcd * 2 + (j & 1), bm = j >> 1;  // bijective; bn-pairs pinned/XCD
  int tid = threadIdx.x, wv = tid >> 6, ln = tid & 63;
  int lr = ln & 15, lg = ln >> 4;
  int R0 = bm * 256, C0 = bn * 128;
  int wr = (wv >> 1) * 64, wc = (wv & 1) * 64;
  // staging: A 4 instr/wave (8 rows each), B 2 instr/wave
  const u16* gA[4];
  int sA[4];
  const u16* gB[2];
  int sB[2];
#pragma unroll
  for (int i = 0; i < 4; ++i) {
    int r = wv * 32 + i * 8 + (ln >> 3);
    int cs = ((ln & 7) ^ (r & 7)) * 8;
    gA[i] = A + (size_t)(R0 + r) * 2048 + cs;
    sA[i] = (wv * 32 + i * 8) * 64;
  }
#pragma unroll
  for (int i = 0; i < 2; ++i) {
    int r = wv * 16 + i * 8 + (ln >> 3);
    int cs = ((ln & 7) ^ (r & 7)) * 8;
    gB[i] = Bw + (size_t)(C0 + r) * 2048 + cs;
    sB[i] = (wv * 16 + i * 8) * 64;
  }
  // ds_read offsets: row*64 + (slot^(row&7))*8, slot = kk*4+lg
  int aoff[4][2], boff[4][2];
#pragma unroll
  for (int i = 0; i < 4; ++i) {
    int ra = wr + i * 16 + lr, rb = wc + i * 16 + lr;
#pragma unroll
    for (int kk = 0; kk < 2; ++kk) {
      aoff[i][kk] = ra * 64 + (((kk * 4 + lg) ^ (ra & 7)) * 8);
      boff[i][kk] = rb * 64 + (((kk * 4 + lg) ^ (rb & 7)) * 8);
    }
  }
  f32x4 acc[4][4] = {};

#define STAGE6(buf, k0)                          \
  {                                              \
    gl_lds(gA[0] + (k0), &AL[buf][sA[0]]);       \
    gl_lds(gA[1] + (k0), &AL[buf][sA[1]]);       \
    gl_lds(gA[2] + (k0), &AL[buf][sA[2]]);       \
    gl_lds(gA[3] + (k0), &AL[buf][sA[3]]);       \
    gl_lds(gB[0] + (k0), &BL[buf][sB[0]]);       \
    gl_lds(gB[1] + (k0), &BL[buf][sB[1]]);       \
  }

  // prologue: stage tiles 0 and 1; validate tile 0 (vmcnt(6): t1 in flight)
  STAGE6(0, 0);
  STAGE6(1, 64);
  asm volatile("s_waitcnt vmcnt(6)" ::: "memory");
  __builtin_amdgcn_s_barrier();

  for (int t = 0; t < 32; ++t) {
    int cur = t % 3, nx2 = (t + 2) % 3;
    int k2 = (t + 2) * 64;
    // ===== phase 0 (kk=0): ds_read + stage half, then MFMA
    bf16x8 a0 = ld16(&AL[cur][aoff[0][0]]), a1 = ld16(&AL[cur][aoff[1][0]]);
    bf16x8 a2 = ld16(&AL[cur][aoff[2][0]]), a3 = ld16(&AL[cur][aoff[3][0]]);
    bf16x8 b0 = ld16(&BL[cur][boff[0][0]]), b1 = ld16(&BL[cur][boff[1][0]]);
    bf16x8 b2 = ld16(&BL[cur][boff[2][0]]), b3 = ld16(&BL[cur][boff[3][0]]);
    if (t < 30) {
      gl_lds(gA[0] + k2, &AL[nx2][sA[0]]);
      gl_lds(gA[1] + k2, &AL[nx2][sA[1]]);
      gl_lds(gB[0] + k2, &BL[nx2][sB[0]]);
    }
    __builtin_amdgcn_s_barrier();
    asm volatile("s_waitcnt lgkmcnt(0)" ::: "memory");
    __builtin_amdgcn_sched_barrier(0);
    __builtin_amdgcn_s_setprio(1);
    acc[0][0] = MFMA16(a0, b0, acc[0][0]);
    acc[0][1] = MFMA16(a0, b1, acc[0][1]);
    acc[0][2] = MFMA16(a0, b2, acc[0][2]);
    acc[0][3] = MFMA16(a0, b3, acc[0][3]);
    acc[1][0] = MFMA16(a1, b0, acc[1][0]);
    acc[1][1] = MFMA16(a1, b1, acc[1][1]);
    acc[1][2] = MFMA16(a1, b2, acc[1][2]);
    acc[1][3] = MFMA16(a1, b3, acc[1][3]);
    acc[2][0] = MFMA16(a2, b0, acc[2][0]);
    acc[2][1] = MFMA16(a2, b1, acc[2][1]);
    acc[2][2] = MFMA16(a2, b2, acc[2][2]);
    acc[2][3] = MFMA16(a2, b3, acc[2][3]);
    acc[3][0] = MFMA16(a3, b0, acc[3][0]);
    acc[3][1] = MFMA16(a3, b1, acc[3][1]);
    acc[3][2] = MFMA16(a3, b2, acc[3][2]);
    acc[3][3] = MFMA16(a3, b3, acc[3][3]);
    __builtin_amdgcn_s_setprio(0);
    __builtin_amdgcn_s_barrier();
    // ===== phase 1 (kk=1): ds_read + stage rest + vmcnt(6), then MFMA
    a0 = ld16(&AL[cur][aoff[0][1]]); a1 = ld16(&AL[cur][aoff[1][1]]);
    a2 = ld16(&AL[cur][aoff[2][1]]); a3 = ld16(&AL[cur][aoff[3][1]]);
    b0 = ld16(&BL[cur][boff[0][1]]); b1 = ld16(&BL[cur][boff[1][1]]);
    b2 = ld16(&BL[cur][boff[2][1]]); b3 = ld16(&BL[cur][boff[3][1]]);
    if (t < 30) {
      gl_lds(gA[2] + k2, &AL[nx2][sA[2]]);
      gl_lds(gA[3] + k2, &AL[nx2][sA[3]]);
      gl_lds(gB[1] + k2, &BL[nx2][sB[1]]);
      asm volatile("s_waitcnt vmcnt(6)" ::: "memory");  // tile t+1 ready
    } else if (t == 30) {
      asm volatile("s_waitcnt vmcnt(0)" ::: "memory");  // drain t31 (tail)
    }
    __builtin_amdgcn_s_barrier();
    asm volatile("s_waitcnt lgkmcnt(0)" ::: "memory");
    __builtin_amdgcn_sched_barrier(0);
    __builtin_amdgcn_s_setprio(1);
    acc[0][0] = MFMA16(a0, b0, acc[0][0]);
    acc[0][1] = MFMA16(a0, b1, acc[0][1]);
    acc[0][2] = MFMA16(a0, b2, acc[0][2]);
    acc[0][3] = MFMA16(a0, b3, acc[0][3]);
    acc[1][0] = MFMA16(a1, b0, acc[1][0]);
    acc[1][1] = MFMA16(a1, b1, acc[1][1]);
    acc[1][2] = MFMA16(a1, b2, acc[1][2]);
    acc[1][3] = MFMA16(a1, b3, acc[1][3]);
    acc[2][0] = MFMA16(a2, b0, acc[2][0]);
    acc[2][1] = MFMA16(a2, b1, acc[2][1]);
    acc[2][2] = MFMA16(a2, b2, acc[2][2]);
    acc[2][3] = MFMA16(a2, b3, acc[2][3]);
    acc[3][0] = MFMA16(a3, b0, acc[3][0]);
    acc[3][1] = MFMA16(a3, b1, acc[3][1]);
    acc[3][2] = MFMA16(a3, b2, acc[3][2]);
    acc[3][3] = MFMA16(a3, b3, acc[3][3]);
    __builtin_amdgcn_s_setprio(0);
    __builtin_amdgcn_s_barrier();
  }
#undef STAGE6
  // epilogue: bias + permuted scatter (bf16 state or f32 final)
#pragma unroll
  for (int nc = 0; nc < 4; ++nc) {
    int e = C0 + wc + nc * 16 + lr;
    float bv = bias[e];
    int i = e >> 8, cc = e & 255;
#pragma unroll
    for (int mt = 0; mt < 4; ++mt)
#pragma unroll
      for (int r = 0; r < 4; ++r) {
        int row = R0 + wr + mt * 16 + lg * 4 + r;
        int nn = row >> 9, jj = row & 511;
        int pos = (8 * jj + i - bsh) & 4095;
        size_t di = ((size_t)nn * 4096 + pos) * 256 + cc;
        float v = acc[mt][nc][r] + bv;
        if (last) doutF[di] = v;
        else doutB[di] = f2bf(v);
      }
  }
}

extern "C" void kernel_launch(void* const* d_in, const int* in_sizes, int n_in,
                              void* d_out, int out_size, void* d_ws, size_t ws_size,
                              hipStream_t stream) {
  const float* M = (const float*)d_in[0];
  const float* Wq = (const float*)d_in[1];
  const float* Wk = (const float*)d_in[2];
  const float* Wv = (const float*)d_in[3];
  const float* fcw = (const float*)d_in[4];
  const float* fcb = (const float*)d_in[5];
  float* out = (float*)d_out;
  char* ws = (char*)d_ws;
  u16* wq_b = (u16*)(ws + (0 << 10));
  u16* wk_b = (u16*)(ws + (32 << 10));
  u16* wv_b = (u16*)(ws + (64 << 10));
  u16* fcw_b = (u16*)(ws + (128 << 10));
  u16* Qb = (u16*)(ws + ((size_t)16 << 20));
  u16* Kb = (u16*)(ws + ((size_t)32 << 20));
  u16* Vtb = (u16*)(ws + ((size_t)48 << 20));
  u16* Ab = (u16*)(ws + ((size_t)64 << 20));
  u16* Sb = (u16*)(ws + ((size_t)96 << 20));  // bf16 state ping (16.8 MB)

  convert_weights<<<4112, 256, 0, stream>>>(Wq, Wk, Wv, fcw, wq_b, wk_b, wv_b, fcw_b);
  for (int b = 0; b < 8; ++b) {
    qkv_kernel<<<dim3(8, 8, 8), 768, 0, stream>>>(M, Sb, (b == 0) ? 1 : 0,
                                                  wq_b, wk_b, wv_b, Qb, Kb, Vtb, b);
    attn_kernel<<<512, 256, 0, stream>>>(Qb, Kb, Vtb, Ab);
    fc_kernel<<<256, 512, 0, stream>>>(Ab, fcw_b, fcb, out, Sb,
                                       (b == 7) ? 1 : 0, b);
  }
}

// Round 10
// 704.625 us; speedup vs baseline: 1.2721x; 1.0134x over previous
//
#include <hip/hip_runtime.h>
#include <stdint.h>

typedef unsigned short u16;
typedef unsigned int u32;
typedef __bf16 bf16x8 __attribute__((ext_vector_type(8)));
typedef float f32x4 __attribute__((ext_vector_type(4)));
typedef float f32x16 __attribute__((ext_vector_type(16)));
typedef u16 u16x4 __attribute__((ext_vector_type(4)));
typedef u16 u16x8 __attribute__((ext_vector_type(8)));

#define MFMA16(a, b, c) __builtin_amdgcn_mfma_f32_16x16x32_bf16(a, b, c, 0, 0, 0)
#define MFMA32(a, b, c) __builtin_amdgcn_mfma_f32_32x32x16_bf16(a, b, c, 0, 0, 0)

__device__ __forceinline__ u16 f2bf(float f) {
  u32 u = __builtin_bit_cast(u32, f);
  u += 0x7FFFu + ((u >> 16) & 1u);
  return (u16)(u >> 16);
}

__device__ __forceinline__ bf16x8 ld16(const u16* p) {
  return __builtin_bit_cast(bf16x8, *(const uint4*)p);
}

__device__ __forceinline__ void gl_lds(const u16* src, u16* lds) {
  __builtin_amdgcn_global_load_lds(
      (const __attribute__((address_space(1))) u32*)src,
      (__attribute__((address_space(3))) u32*)lds, 16, 0, 0);
}

// ------- weight conversion + one-time M(f32)->Sb(bf16) state convert -------
__global__ __launch_bounds__(256) void convert_weights(
    const float* __restrict__ Wq, const float* __restrict__ Wk,
    const float* __restrict__ Wv, const float* __restrict__ fcw,
    const float* __restrict__ M, u16* __restrict__ wq_b,
    u16* __restrict__ wk_b, u16* __restrict__ wv_b, u16* __restrict__ fcw_b,
    u16* __restrict__ Sb) {
  int bx = blockIdx.x, tid = threadIdx.x;
  if (bx < 4096) {
    int i = (bx * 256 + tid) * 4;
    float4 f = *(const float4*)&fcw[i];
    u16x4 o = {f2bf(f.x), f2bf(f.y), f2bf(f.z), f2bf(f.w)};
    *(u16x4*)&fcw_b[i] = o;
  } else if (bx < 4112) {
    int i = ((bx - 4096) * 256 + tid) * 4;
    const float sc = 0.022097086912079612f;  // 1/sqrt(2048) folded into Wq
    float4 q = *(const float4*)&Wq[i];
    u16x4 oq = {f2bf(q.x * sc), f2bf(q.y * sc), f2bf(q.z * sc), f2bf(q.w * sc)};
    *(u16x4*)&wq_b[i] = oq;
    float4 k = *(const float4*)&Wk[i];
    u16x4 ok = {f2bf(k.x), f2bf(k.y), f2bf(k.z), f2bf(k.w)};
    *(u16x4*)&wk_b[i] = ok;
    float4 v = *(const float4*)&Wv[i];
    u16x4 ov = {f2bf(v.x), f2bf(v.y), f2bf(v.z), f2bf(v.w)};
    *(u16x4*)&wv_b[i] = ov;
  } else {
    size_t i = ((size_t)(bx - 4112) * 256 + tid) * 8;
    float4 f0 = *(const float4*)&M[i];
    float4 f1 = *(const float4*)&M[i + 4];
    u16x8 v = {f2bf(f0.x), f2bf(f0.y), f2bf(f0.z), f2bf(f0.w),
               f2bf(f1.x), f2bf(f1.y), f2bf(f1.z), f2bf(f1.w)};
    *(u16x8*)&Sb[i] = v;
  }
}

// ---------------- KV projection, 2 heads per block (Q fused into attn) -----
// Grid (jt=8, i0=8, n=8), 512 threads (8 waves): mat=w>>2 (0=K,1=V),
// hc=w&3 -> head hh=hc>>1, col-half cb=(hc&1)*64.
__global__ __launch_bounds__(512) void kv_kernel(
    const u16* __restrict__ srcB, const u16* __restrict__ wk,
    const u16* __restrict__ wvw, u16* __restrict__ K, u16* __restrict__ Vt,
    int bsh) {
  __shared__ u16 X[64 * 264];
  int jt = blockIdx.x, i0 = blockIdx.y, n = blockIdx.z;
  int tid = threadIdx.x;
#pragma unroll
  for (int it = 0; it < 4; ++it) {
    int c = tid + it * 512;
    int row = c >> 5, seg = c & 31;
    int pos = (8 * (jt * 64 + row) + i0 - bsh) & 4095;
    size_t base = ((size_t)n * 4096 + pos) * 256 + seg * 8;
    *(u16x8*)&X[row * 264 + seg * 8] = *(const u16x8*)&srcB[base];
  }
  __syncthreads();
  int wvid = tid >> 6, ln = tid & 63;
  int mat = wvid >> 2, hc = wvid & 3;
  int hh = hc >> 1, cb = (hc & 1) * 64;
  int h = i0 * 2 + hh, xc = hh * 128;
  const u16* W = (mat == 0) ? wk : wvw;
  int lr = ln & 15, lg = ln >> 4;
  f32x4 acc[4][4] = {};
#pragma unroll
  for (int kt = 0; kt < 4; ++kt) {
    bf16x8 a[4], b[4];
#pragma unroll
    for (int mt = 0; mt < 4; ++mt)
      a[mt] = ld16(&X[(mt * 16 + lr) * 264 + xc + kt * 32 + lg * 8]);
#pragma unroll
    for (int nc = 0; nc < 4; ++nc)
      b[nc] = ld16(&W[(cb + nc * 16 + lr) * 128 + kt * 32 + lg * 8]);
#pragma unroll
    for (int mt = 0; mt < 4; ++mt)
#pragma unroll
      for (int nc = 0; nc < 4; ++nc)
        acc[mt][nc] = MFMA16(a[mt], b[nc], acc[mt][nc]);
  }
  size_t nh = (size_t)(n * 16 + h);
  if (mat == 0) {
    u16* dst = K + nh * 512 * 128;
#pragma unroll
    for (int mt = 0; mt < 4; ++mt)
#pragma unroll
      for (int nc = 0; nc < 4; ++nc) {
        int col = cb + nc * 16 + lr;
        int jb = jt * 64 + mt * 16 + lg * 4;
#pragma unroll
        for (int r = 0; r < 4; ++r)
          dst[(size_t)(jb + r) * 128 + col] = f2bf(acc[mt][nc][r]);
      }
  } else {
    u16* dst = Vt + nh * 128 * 512;
#pragma unroll
    for (int mt = 0; mt < 4; ++mt)
#pragma unroll
      for (int nc = 0; nc < 4; ++nc) {
        int col = cb + nc * 16 + lr;
        int jb = jt * 64 + mt * 16 + lg * 4;
        u16x4 pk = {f2bf(acc[mt][nc][0]), f2bf(acc[mt][nc][1]),
                    f2bf(acc[mt][nc][2]), f2bf(acc[mt][nc][3])};
        *(u16x4*)&dst[(size_t)col * 512 + jb] = pk;
      }
  }
}

// ---------------- flash attention with fused Q-projection ----------------
// Prologue: gather X (128 tokens x 128ch, per-lane-source gl_lds) + Wq into
// the K/V LDS union; qd = Wq . X^T (32 MFMA32); relayout D->B-frag via the
// verified cvt_pk+permlane pattern (same index algebra as pa[]).
// Main loop: T15 att[2] pipeline, unchanged.
__global__ __launch_bounds__(256, 2) void attn_kernel(
    const u16* __restrict__ Sb, const u16* __restrict__ wq,
    const u16* __restrict__ K, const u16* __restrict__ Vt,
    u16* __restrict__ O, int bsh) {
  __shared__ u16 SMEM[40960];  // 80KB: KL[3] @0, VL[2] @24576; Xq/Wq union
#define KLp(b) (&SMEM[(b) * 8192])
#define VLp(b) (&SMEM[24576 + (b) * 8192])
  int flat = blockIdx.x;
  int xcd = flat & 7, idx = flat >> 3;
  int gl = idx & 15, qt = idx >> 4;
  int g = xcd | (gl << 3);
  int h = g & 15, n = g >> 4;
  int tid = threadIdx.x, wv = tid >> 6, ln = tid & 63;
  int l31 = ln & 31, hh = ln >> 5;
  size_t nh = (size_t)(n * 16 + h);
  int q0 = qt * 128 + wv * 32;
  const u16* Kb = K + (size_t)nh * 512 * 128;
  const u16* Vb = Vt + (size_t)nh * 128 * 512;
  int i0h = h >> 1, c0 = (h & 1) * 128;

  // ---- stage Xq (gathered state rows) and Wq into SMEM[0..32768) ----
#pragma unroll
  for (int i = 0; i < 8; ++i) {
    int s = wv * 8 + i;
    int r = 4 * s + (ln >> 4);
    int slot = (ln & 15) ^ (r & 15);
    int pos = (8 * (qt * 128 + r) + i0h - bsh) & 4095;
    gl_lds(&Sb[((size_t)n * 4096 + pos) * 256 + c0 + slot * 8], &SMEM[s * 512]);
    gl_lds(&wq[r * 128 + slot * 8], &SMEM[16384 + s * 512]);
  }
  __syncthreads();
  // ---- Q-projection: qd[eb] = Wq-rows x X-rows^T (D: col=l31=j, crow=e) ----
  f32x16 qd[4] = {};
  int jr = wv * 32 + l31;
#pragma unroll
  for (int cs = 0; cs < 8; ++cs) {
    bf16x8 xf = ld16(&SMEM[jr * 128 + ((2 * cs + hh) ^ (jr & 15)) * 8]);
#pragma unroll
    for (int eb = 0; eb < 4; ++eb) {
      int er = eb * 32 + l31;
      bf16x8 wf = ld16(&SMEM[16384 + er * 128 + ((2 * cs + hh) ^ (er & 15)) * 8]);
      qd[eb] = MFMA32(wf, xf, qd[eb]);
    }
  }
  // ---- relayout qd -> qf (B-frag: lane holds Q[j=l31][kt*16+hh*8+0..7]) ----
  bf16x8 qf[8];
#pragma unroll
  for (int kt = 0; kt < 8; ++kt) {
    const int eb = kt >> 1, r0 = 8 * (kt & 1);
    u32 wA, wB, wC, wD;
    asm("v_cvt_pk_bf16_f32 %0, %1, %2" : "=v"(wA) : "v"(qd[eb][r0 + 0]), "v"(qd[eb][r0 + 1]));
    asm("v_cvt_pk_bf16_f32 %0, %1, %2" : "=v"(wB) : "v"(qd[eb][r0 + 2]), "v"(qd[eb][r0 + 3]));
    asm("v_cvt_pk_bf16_f32 %0, %1, %2" : "=v"(wC) : "v"(qd[eb][r0 + 4]), "v"(qd[eb][r0 + 5]));
    asm("v_cvt_pk_bf16_f32 %0, %1, %2" : "=v"(wD) : "v"(qd[eb][r0 + 6]), "v"(qd[eb][r0 + 7]));
    asm("v_permlane32_swap_b32 %0, %1" : "+v"(wA), "+v"(wC));
    asm("v_permlane32_swap_b32 %0, %1" : "+v"(wB), "+v"(wD));
    uint4 ww = {wA, wB, wC, wD};
    qf[kt] = __builtin_bit_cast(bf16x8, ww);
  }
  __syncthreads();  // all waves done reading Xq/Wq before K/V staging

  // per-wave K/V staging geometry (source-side XOR swizzle, rule #21)
  int l16 = ln & 15, l8 = ln & 7;
  int rK[4], cK[4], rV[4], cV[4];
#pragma unroll
  for (int i = 0; i < 4; ++i) {
    int s = wv * 4 + i;
    rK[i] = 4 * s + (ln >> 4);
    cK[i] = (l16 ^ (rK[i] & 15)) * 8;
    rV[i] = 8 * s + (ln >> 3);
    cV[i] = (l8 ^ (rV[i] & 7)) * 8;
  }

#define STAGE_K(buf, kv)                                                     \
  {                                                                          \
    const u16* kp_ = Kb + (size_t)(kv) * 64 * 128;                           \
    _Pragma("unroll") for (int i_ = 0; i_ < 4; ++i_) {                       \
      int s_ = wv * 4 + i_;                                                  \
      gl_lds(&kp_[(size_t)rK[i_] * 128 + cK[i_]], &KLp(buf)[s_ * 512]);      \
    }                                                                        \
  }
#define STAGE_V(buf, kv)                                                     \
  {                                                                          \
    _Pragma("unroll") for (int i_ = 0; i_ < 4; ++i_) {                       \
      int s_ = wv * 4 + i_;                                                  \
      gl_lds(&Vb[(size_t)rV[i_] * 512 + (kv)*64 + cV[i_]], &VLp(buf)[s_ * 512]); \
    }                                                                        \
  }

  STAGE_K(0, 0);
  STAGE_V(0, 0);
  STAGE_K(1, 1);
  __syncthreads();

  f32x16 ps[2][2];
  f32x16 o[4] = {};
  float m = -1e30f, l = 0.f;

  {
    f32x16 z = {};
    ps[0][0] = z; ps[0][1] = z;
#pragma unroll
    for (int kt = 0; kt < 8; ++kt) {
      int slot0 = (2 * kt + hh) ^ (l31 & 15);
      bf16x8 a0 = ld16(&KLp(0)[l31 * 128 + slot0 * 8]);
      ps[0][0] = MFMA32(a0, qf[kt], ps[0][0]);
      int row1 = 32 + l31;
      int slot1 = (2 * kt + hh) ^ (row1 & 15);
      bf16x8 a1 = ld16(&KLp(0)[row1 * 128 + slot1 * 8]);
      ps[0][1] = MFMA32(a1, qf[kt], ps[0][1]);
    }
  }

#pragma unroll
  for (int t = 0; t < 8; ++t) {
    const int cur = t & 1, nxt = (t + 1) & 1;
    if (t + 2 <= 7) STAGE_K((t + 2) % 3, t + 2);
    if (t + 1 <= 7) STAGE_V(nxt, t + 1);
    if (t + 1 <= 7) {
      const int kb = (t + 1) % 3;
      f32x16 z = {};
      ps[nxt][0] = z; ps[nxt][1] = z;
#pragma unroll
      for (int kt = 0; kt < 8; ++kt) {
        int slot0 = (2 * kt + hh) ^ (l31 & 15);
        bf16x8 a0 = ld16(&KLp(kb)[l31 * 128 + slot0 * 8]);
        ps[nxt][0] = MFMA32(a0, qf[kt], ps[nxt][0]);
        int row1 = 32 + l31;
        int slot1 = (2 * kt + hh) ^ (row1 & 15);
        bf16x8 a1 = ld16(&KLp(kb)[row1 * 128 + slot1 * 8]);
        ps[nxt][1] = MFMA32(a1, qf[kt], ps[nxt][1]);
      }
    }
    float mx[8];
#pragma unroll
    for (int i = 0; i < 8; ++i)
      mx[i] = fmaxf(fmaxf(ps[cur][0][2 * i], ps[cur][0][2 * i + 1]),
                    fmaxf(ps[cur][1][2 * i], ps[cur][1][2 * i + 1]));
    float pm = fmaxf(fmaxf(fmaxf(mx[0], mx[1]), fmaxf(mx[2], mx[3])),
                     fmaxf(fmaxf(mx[4], mx[5]), fmaxf(mx[6], mx[7])));
    pm = fmaxf(pm, __shfl_xor(pm, 32));
    if (!__all(pm <= m + 8.f)) {
      float nm = fmaxf(m, pm);
      float al = __expf(m - nm);
      l *= al;
      m = nm;
#pragma unroll
      for (int r = 0; r < 16; ++r) {
        int qr = (r & 3) + 8 * (r >> 2) + 4 * hh;
        float av = __shfl(al, (ln & 32) | qr, 64);
        o[0][r] *= av; o[1][r] *= av; o[2][r] *= av; o[3][r] *= av;
      }
    }
#pragma unroll
    for (int kb2 = 0; kb2 < 2; ++kb2)
#pragma unroll
      for (int r = 0; r < 16; ++r)
        ps[cur][kb2][r] = __expf(ps[cur][kb2][r] - m);
    float sm[8];
#pragma unroll
    for (int i = 0; i < 8; ++i)
      sm[i] = (ps[cur][0][2 * i] + ps[cur][0][2 * i + 1]) +
              (ps[cur][1][2 * i] + ps[cur][1][2 * i + 1]);
    float rs = ((sm[0] + sm[1]) + (sm[2] + sm[3])) +
               ((sm[4] + sm[5]) + (sm[6] + sm[7]));
    rs += __shfl_xor(rs, 32);
    l += rs;
    bf16x8 pa[4];
#pragma unroll
    for (int ks = 0; ks < 4; ++ks) {
      const int kb2 = ks >> 1, r0 = 8 * (ks & 1);
      u32 wA, wB, wC, wD;
      asm("v_cvt_pk_bf16_f32 %0, %1, %2" : "=v"(wA) : "v"(ps[cur][kb2][r0 + 0]), "v"(ps[cur][kb2][r0 + 1]));
      asm("v_cvt_pk_bf16_f32 %0, %1, %2" : "=v"(wB) : "v"(ps[cur][kb2][r0 + 2]), "v"(ps[cur][kb2][r0 + 3]));
      asm("v_cvt_pk_bf16_f32 %0, %1, %2" : "=v"(wC) : "v"(ps[cur][kb2][r0 + 4]), "v"(ps[cur][kb2][r0 + 5]));
      asm("v_cvt_pk_bf16_f32 %0, %1, %2" : "=v"(wD) : "v"(ps[cur][kb2][r0 + 6]), "v"(ps[cur][kb2][r0 + 7]));
      asm("v_permlane32_swap_b32 %0, %1" : "+v"(wA), "+v"(wC));
      asm("v_permlane32_swap_b32 %0, %1" : "+v"(wB), "+v"(wD));
      uint4 ww = {wA, wB, wC, wD};
      pa[ks] = __builtin_bit_cast(bf16x8, ww);
    }
    __builtin_amdgcn_s_setprio(1);
#pragma unroll
    for (int ks = 0; ks < 4; ++ks)
#pragma unroll
      for (int nb = 0; nb < 4; ++nb) {
        int row = nb * 32 + l31;
        int slot = (2 * ks + hh) ^ (row & 7);
        bf16x8 bv = ld16(&VLp(cur)[row * 64 + slot * 8]);
        o[nb] = MFMA32(pa[ks], bv, o[nb]);
      }
    __builtin_amdgcn_s_setprio(0);
    if (t < 7) __syncthreads();
  }
#undef STAGE_K
#undef STAGE_V
#undef KLp
#undef VLp

  float inv = 1.f / l;
#pragma unroll
  for (int r = 0; r < 16; ++r) {
    int qr = (r & 3) + 8 * (r >> 2) + 4 * hh;
    float iv = __shfl(inv, (ln & 32) | qr, 64);
    int row = q0 + qr;
    u16* dst = O + ((size_t)n * 512 + row) * 2048 + h * 128;
    dst[0 * 32 + l31] = f2bf(o[0][r] * iv);
    dst[1 * 32 + l31] = f2bf(o[1][r] * iv);
    dst[2 * 32 + l31] = f2bf(o[2][r] * iv);
    dst[3 * 32 + l31] = f2bf(o[3][r] * iv);
  }
}

// ---------------- FC GEMM (R9 structure, unchanged) ----------------
__global__ __launch_bounds__(512, 1) void fc_kernel(
    const u16* __restrict__ A, const u16* __restrict__ Bw,
    const float* __restrict__ bias, float* __restrict__ doutF,
    u16* __restrict__ doutB, int last, int bsh) {
  __shared__ u16 AL[3][256 * 64];
  __shared__ u16 BL[3][128 * 64];
  int blk = blockIdx.x;
  int xcd = blk & 7, j = blk >> 3;
  int bn = xcd * 2 + (j & 1), bm = j >> 1;
  int tid = threadIdx.x, wv = tid >> 6, ln = tid & 63;
  int lr = ln & 15, lg = ln >> 4;
  int R0 = bm * 256, C0 = bn * 128;
  int wr = (wv >> 1) * 64, wc = (wv & 1) * 64;
  const u16* gA[4];
  int sA[4];
  const u16* gB[2];
  int sB[2];
#pragma unroll
  for (int i = 0; i < 4; ++i) {
    int r = wv * 32 + i * 8 + (ln >> 3);
    int cs = ((ln & 7) ^ (r & 7)) * 8;
    gA[i] = A + (size_t)(R0 + r) * 2048 + cs;
    sA[i] = (wv * 32 + i * 8) * 64;
  }
#pragma unroll
  for (int i = 0; i < 2; ++i) {
    int r = wv * 16 + i * 8 + (ln >> 3);
    int cs = ((ln & 7) ^ (r & 7)) * 8;
    gB[i] = Bw + (size_t)(C0 + r) * 2048 + cs;
    sB[i] = (wv * 16 + i * 8) * 64;
  }
  int aoff[4][2], boff[4][2];
#pragma unroll
  for (int i = 0; i < 4; ++i) {
    int ra = wr + i * 16 + lr, rb = wc + i * 16 + lr;
#pragma unroll
    for (int kk = 0; kk < 2; ++kk) {
      aoff[i][kk] = ra * 64 + (((kk * 4 + lg) ^ (ra & 7)) * 8);
      boff[i][kk] = rb * 64 + (((kk * 4 + lg) ^ (rb & 7)) * 8);
    }
  }
  f32x4 acc[4][4] = {};

#define STAGE6(buf, k0)                          \
  {                                              \
    gl_lds(gA[0] + (k0), &AL[buf][sA[0]]);       \
    gl_lds(gA[1] + (k0), &AL[buf][sA[1]]);       \
    gl_lds(gA[2] + (k0), &AL[buf][sA[2]]);       \
    gl_lds(gA[3] + (k0), &AL[buf][sA[3]]);       \
    gl_lds(gB[0] + (k0), &BL[buf][sB[0]]);       \
    gl_lds(gB[1] + (k0), &BL[buf][sB[1]]);       \
  }

  STAGE6(0, 0);
  STAGE6(1, 64);
  asm volatile("s_waitcnt vmcnt(6)" ::: "memory");
  __builtin_amdgcn_s_barrier();

  for (int t = 0; t < 32; ++t) {
    int cur = t % 3, nx2 = (t + 2) % 3;
    int k2 = (t + 2) * 64;
    bf16x8 a0 = ld16(&AL[cur][aoff[0][0]]), a1 = ld16(&AL[cur][aoff[1][0]]);
    bf16x8 a2 = ld16(&AL[cur][aoff[2][0]]), a3 = ld16(&AL[cur][aoff[3][0]]);
    bf16x8 b0 = ld16(&BL[cur][boff[0][0]]), b1 = ld16(&BL[cur][boff[1][0]]);
    bf16x8 b2 = ld16(&BL[cur][boff[2][0]]), b3 = ld16(&BL[cur][boff[3][0]]);
    if (t < 30) {
      gl_lds(gA[0] + k2, &AL[nx2][sA[0]]);
      gl_lds(gA[1] + k2, &AL[nx2][sA[1]]);
      gl_lds(gB[0] + k2, &BL[nx2][sB[0]]);
    }
    __builtin_amdgcn_s_barrier();
    asm volatile("s_waitcnt lgkmcnt(0)" ::: "memory");
    __builtin_amdgcn_sched_barrier(0);
    __builtin_amdgcn_s_setprio(1);
    acc[0][0] = MFMA16(a0, b0, acc[0][0]);
    acc[0][1] = MFMA16(a0, b1, acc[0][1]);
    acc[0][2] = MFMA16(a0, b2, acc[0][2]);
    acc[0][3] = MFMA16(a0, b3, acc[0][3]);
    acc[1][0] = MFMA16(a1, b0, acc[1][0]);
    acc[1][1] = MFMA16(a1, b1, acc[1][1]);
    acc[1][2] = MFMA16(a1, b2, acc[1][2]);
    acc[1][3] = MFMA16(a1, b3, acc[1][3]);
    acc[2][0] = MFMA16(a2, b0, acc[2][0]);
    acc[2][1] = MFMA16(a2, b1, acc[2][1]);
    acc[2][2] = MFMA16(a2, b2, acc[2][2]);
    acc[2][3] = MFMA16(a2, b3, acc[2][3]);
    acc[3][0] = MFMA16(a3, b0, acc[3][0]);
    acc[3][1] = MFMA16(a3, b1, acc[3][1]);
    acc[3][2] = MFMA16(a3, b2, acc[3][2]);
    acc[3][3] = MFMA16(a3, b3, acc[3][3]);
    __builtin_amdgcn_s_setprio(0);
    __builtin_amdgcn_s_barrier();
    a0 = ld16(&AL[cur][aoff[0][1]]); a1 = ld16(&AL[cur][aoff[1][1]]);
    a2 = ld16(&AL[cur][aoff[2][1]]); a3 = ld16(&AL[cur][aoff[3][1]]);
    b0 = ld16(&BL[cur][boff[0][1]]); b1 = ld16(&BL[cur][boff[1][1]]);
    b2 = ld16(&BL[cur][boff[2][1]]); b3 = ld16(&BL[cur][boff[3][1]]);
    if (t < 30) {
      gl_lds(gA[2] + k2, &AL[nx2][sA[2]]);
      gl_lds(gA[3] + k2, &AL[nx2][sA[3]]);
      gl_lds(gB[1] + k2, &BL[nx2][sB[1]]);
      asm volatile("s_waitcnt vmcnt(6)" ::: "memory");
    } else if (t == 30) {
      asm volatile("s_waitcnt vmcnt(0)" ::: "memory");
    }
    __builtin_amdgcn_s_barrier();
    asm volatile("s_waitcnt lgkmcnt(0)" ::: "memory");
    __builtin_amdgcn_sched_barrier(0);
    __builtin_amdgcn_s_setprio(1);
    acc[0][0] = MFMA16(a0, b0, acc[0][0]);
    acc[0][1] = MFMA16(a0, b1, acc[0][1]);
    acc[0][2] = MFMA16(a0, b2, acc[0][2]);
    acc[0][3] = MFMA16(a0, b3, acc[0][3]);
    acc[1][0] = MFMA16(a1, b0, acc[1][0]);
    acc[1][1] = MFMA16(a1, b1, acc[1][1]);
    acc[1][2] = MFMA16(a1, b2, acc[1][2]);
    acc[1][3] = MFMA16(a1, b3, acc[1][3]);
    acc[2][0] = MFMA16(a2, b0, acc[2][0]);
    acc[2][1] = MFMA16(a2, b1, acc[2][1]);
    acc[2][2] = MFMA16(a2, b2, acc[2][2]);
    acc[2][3] = MFMA16(a2, b3, acc[2][3]);
    acc[3][0] = MFMA16(a3, b0, acc[3][0]);
    acc[3][1] = MFMA16(a3, b1, acc[3][1]);
    acc[3][2] = MFMA16(a3, b2, acc[3][2]);
    acc[3][3] = MFMA16(a3, b3, acc[3][3]);
    __builtin_amdgcn_s_setprio(0);
    __builtin_amdgcn_s_barrier();
  }
#undef STAGE6
#pragma unroll
  for (int nc = 0; nc < 4; ++nc) {
    int e = C0 + wc + nc * 16 + lr;
    float bv = bias[e];
    int i = e >> 8, cc = e & 255;
#pragma unroll
    for (int mt = 0; mt < 4; ++mt)
#pragma unroll
      for (int r = 0; r < 4; ++r) {
        int row = R0 + wr + mt * 16 + lg * 4 + r;
        int nn = row >> 9, jj = row & 511;
        int pos = (8 * jj + i - bsh) & 4095;
        size_t di = ((size_t)nn * 4096 + pos) * 256 + cc;
        float v = acc[mt][nc][r] + bv;
        if (last) doutF[di] = v;
        else doutB[di] = f2bf(v);
      }
  }
}

extern "C" void kernel_launch(void* const* d_in, const int* in_sizes, int n_in,
                              void* d_out, int out_size, void* d_ws, size_t ws_size,
                              hipStream_t stream) {
  const float* M = (const float*)d_in[0];
  const float* Wq = (const float*)d_in[1];
  const float* Wk = (const float*)d_in[2];
  const float* Wv = (const float*)d_in[3];
  const float* fcw = (const float*)d_in[4];
  const float* fcb = (const float*)d_in[5];
  float* out = (float*)d_out;
  char* ws = (char*)d_ws;
  u16* wq_b = (u16*)(ws + (0 << 10));
  u16* wk_b = (u16*)(ws + (32 << 10));
  u16* wv_b = (u16*)(ws + (64 << 10));
  u16* fcw_b = (u16*)(ws + (128 << 10));
  u16* Kb = (u16*)(ws + ((size_t)32 << 20));
  u16* Vtb = (u16*)(ws + ((size_t)48 << 20));
  u16* Ab = (u16*)(ws + ((size_t)64 << 20));
  u16* Sb = (u16*)(ws + ((size_t)96 << 20));  // bf16 state (16.8 MB)

  convert_weights<<<8208, 256, 0, stream>>>(Wq, Wk, Wv, fcw, M, wq_b, wk_b,
                                            wv_b, fcw_b, Sb);
  for (int b = 0; b < 8; ++b) {
    kv_kernel<<<dim3(8, 8, 8), 512, 0, stream>>>(Sb, wk_b, wv_b, Kb, Vtb, b);
    attn_kernel<<<512, 256, 0, stream>>>(Sb, wq_b, Kb, Vtb, Ab, b);
    fc_kernel<<<256, 512, 0, stream>>>(Ab, fcw_b, fcb, out, Sb,
                                       (b == 7) ? 1 : 0, b);
  }
}